// Round 1
// baseline (2368.016 us; speedup 1.0000x reference)
//
#include <hip/hip_runtime.h>
#include <hip/hip_bf16.h>

// GraphSAGE 2-layer forward, MI355X.
// Layer1: agg1 = mean_{src->dst} x[src];  h = relu(agg1@W1l + x@W1r + b1)
// Layer2: hp = h@W2l (project BEFORE aggregating: linearity halves scatter bytes)
//         out = mean(hp) + b2 + h@W2r

#define N_NODES 50000
#define IN_C    128
#define HID_C   256
#define OUT_C   128
#define N_EDGES 600000

#define BM 64
#define BN 64
#define BK 32

__global__ void count_deg(const int* __restrict__ dst, int* __restrict__ cnt, int E) {
    int e = blockIdx.x * blockDim.x + threadIdx.x;
    if (e < E) atomicAdd(&cnt[dst[e]], 1);
}

// feat is [*, 128]; one thread per (edge, 4-channel chunk); 32 chunks/edge
__global__ void scatter_add128(const float* __restrict__ feat,
                               const int* __restrict__ srcIdx,
                               const int* __restrict__ dstIdx,
                               float* __restrict__ agg, int E) {
    int tid = blockIdx.x * blockDim.x + threadIdx.x;
    if (tid >= E * 32) return;
    int e = tid >> 5;
    int c = (tid & 31) * 4;
    int s = srcIdx[e];
    int d = dstIdx[e];
    float4 v = *(const float4*)(feat + (size_t)s * 128 + c);
    float* p = agg + (size_t)d * 128 + c;
    atomicAdd(p + 0, v.x);
    atomicAdd(p + 1, v.y);
    atomicAdd(p + 2, v.z);
    atomicAdd(p + 3, v.w);
}

// agg[node][c] /= max(cnt[node],1); one float4 per thread, 128 floats/node
__global__ void normalize128(float* __restrict__ agg, const int* __restrict__ cnt, int n4) {
    int t = blockIdx.x * blockDim.x + threadIdx.x;
    if (t >= n4) return;
    int node = t >> 5;                  // 32 float4 per node
    float inv = 1.0f / (float)max(cnt[node], 1);
    float4* p = (float4*)agg + t;
    float4 v = *p;
    v.x *= inv; v.y *= inv; v.z *= inv; v.w *= inv;
    *p = v;
}

// C[M,N] = [A0 | A1] @ [B0 ; B1] (+ bias) (+ addend) (relu?)
// A0: [M,k0], A1: [M,k1] (may be null, k1=0), B0: [k0,N], B1: [k1,N]
// k0,k1 multiples of BK so each K-tile comes wholly from one source.
__global__ __launch_bounds__(256) void sage_gemm(
    const float* __restrict__ A0, const float* __restrict__ B0, int k0,
    const float* __restrict__ A1, const float* __restrict__ B1, int k1,
    const float* __restrict__ bias, const float* __restrict__ addend,
    float* __restrict__ Cout, int M, int N, int relu) {
    const int K = k0 + k1;
    __shared__ float As[BK][BM + 4];   // transposed: As[k][m], pad 4 keeps 16B align
    __shared__ float Bs[BK][BN + 4];

    int tid = threadIdx.x;
    int tx = tid & 15;    // n micro index
    int ty = tid >> 4;    // m micro index
    int mb = blockIdx.x * BM;
    int nb = blockIdx.y * BN;

    // A-tile load map: row = tid>>2 (0..63), k-chunk start = (tid&3)*8
    int a_row = tid >> 2;
    int a_kc  = (tid & 3) * 8;
    // B-tile load map: k row = tid>>3 (0..31), n start = (tid&7)*8
    int b_kr = tid >> 3;
    int b_nc = (tid & 7) * 8;

    float acc[4][4] = {{0.f}};

    for (int kt = 0; kt < K; kt += BK) {
        // ---- stage A (64 rows x 32 k), store transposed ----
        int gm = mb + a_row;
        #pragma unroll
        for (int hh = 0; hh < 2; ++hh) {
            int kk = a_kc + hh * 4;
            int gk = kt + kk;
            float4 v = make_float4(0.f, 0.f, 0.f, 0.f);
            if (gm < M) {
                if (gk < k0) v = *(const float4*)(A0 + (size_t)gm * k0 + gk);
                else         v = *(const float4*)(A1 + (size_t)gm * k1 + (gk - k0));
            }
            As[kk + 0][a_row] = v.x;
            As[kk + 1][a_row] = v.y;
            As[kk + 2][a_row] = v.z;
            As[kk + 3][a_row] = v.w;
        }
        // ---- stage B (32 k x 64 n) ----
        #pragma unroll
        for (int hh = 0; hh < 2; ++hh) {
            int nn = b_nc + hh * 4;
            int gk = kt + b_kr;
            float4 v;
            if (gk < k0) v = *(const float4*)(B0 + (size_t)gk * N + nb + nn);
            else         v = *(const float4*)(B1 + (size_t)(gk - k0) * N + nb + nn);
            *(float4*)&Bs[b_kr][nn] = v;
        }
        __syncthreads();

        #pragma unroll
        for (int k = 0; k < BK; ++k) {
            float a[4], b[4];
            *(float4*)a = *(const float4*)&As[k][ty * 4];
            *(float4*)b = *(const float4*)&Bs[k][tx * 4];
            #pragma unroll
            for (int i = 0; i < 4; ++i)
                #pragma unroll
                for (int j = 0; j < 4; ++j)
                    acc[i][j] = fmaf(a[i], b[j], acc[i][j]);
        }
        __syncthreads();
    }

    // ---- epilogue ----
    #pragma unroll
    for (int i = 0; i < 4; ++i) {
        int gm = mb + ty * 4 + i;
        if (gm >= M) continue;
        #pragma unroll
        for (int j = 0; j < 4; ++j) {
            int gn = nb + tx * 4 + j;
            float v = acc[i][j];
            if (bias)   v += bias[gn];
            if (addend) v += addend[(size_t)gm * N + gn];
            if (relu)   v = fmaxf(v, 0.f);
            Cout[(size_t)gm * N + gn] = v;
        }
    }
}

extern "C" void kernel_launch(void* const* d_in, const int* in_sizes, int n_in,
                              void* d_out, int out_size, void* d_ws, size_t ws_size,
                              hipStream_t stream) {
    const float* x    = (const float*)d_in[0];
    const int*   ei   = (const int*)d_in[1];    // [2, E] flat; harness gives int32
    const float* W1l  = (const float*)d_in[2];  // [128,256]
    const float* b1   = (const float*)d_in[3];  // [256]
    const float* W1r  = (const float*)d_in[4];  // [128,256]
    const float* W2l  = (const float*)d_in[5];  // [256,128]
    const float* b2   = (const float*)d_in[6];  // [128]
    const float* W2r  = (const float*)d_in[7];  // [256,128]
    float* out = (float*)d_out;

    const int E = N_EDGES;
    const int* srcI = ei;
    const int* dstI = ei + E;

    // workspace layout
    char* w = (char*)d_ws;
    int*   cnt = (int*)w;                                           // 200 KB (pad to 256KB)
    float* agg = (float*)(w + (256 << 10));                         // 25.6 MB (reused L1+L2)
    float* h   = (float*)(w + (256 << 10) + 25600000);              // 51.2 MB
    float* hp  = (float*)(w + (256 << 10) + 25600000 + 51200000);   // 25.6 MB

    const size_t aggBytes = (size_t)N_NODES * IN_C * sizeof(float); // 25.6 MB (128-wide)

    // ---- degree (shared by both layers) ----
    hipMemsetAsync(cnt, 0, N_NODES * sizeof(int), stream);
    hipMemsetAsync(agg, 0, aggBytes, stream);
    count_deg<<<(E + 255) / 256, 256, 0, stream>>>(dstI, cnt, E);

    // ---- layer 1 ----
    scatter_add128<<<(E * 32 + 255) / 256, 256, 0, stream>>>(x, srcI, dstI, agg, E);
    normalize128<<<(N_NODES * 32 + 255) / 256, 256, 0, stream>>>(agg, cnt, N_NODES * 32);
    {
        dim3 grid((N_NODES + BM - 1) / BM, HID_C / BN);
        sage_gemm<<<grid, 256, 0, stream>>>(agg, W1l, IN_C, x, W1r, IN_C,
                                            b1, nullptr, h, N_NODES, HID_C, 1);
    }

    // ---- layer 2: project first (hp = h @ W2l), then aggregate 128-dim ----
    {
        dim3 grid((N_NODES + BM - 1) / BM, OUT_C / BN);
        sage_gemm<<<grid, 256, 0, stream>>>(h, W2l, HID_C, nullptr, nullptr, 0,
                                            nullptr, nullptr, hp, N_NODES, OUT_C, 0);
    }
    hipMemsetAsync(agg, 0, aggBytes, stream);
    scatter_add128<<<(E * 32 + 255) / 256, 256, 0, stream>>>(hp, srcI, dstI, agg, E);
    normalize128<<<(N_NODES * 32 + 255) / 256, 256, 0, stream>>>(agg, cnt, N_NODES * 32);
    {
        dim3 grid((N_NODES + BM - 1) / BM, OUT_C / BN);
        sage_gemm<<<grid, 256, 0, stream>>>(h, W2r, HID_C, nullptr, nullptr, 0,
                                            b2, agg, out, N_NODES, OUT_C, 0);
    }
}

// Round 2
// 460.092 us; speedup vs baseline: 5.1468x; 5.1468x over previous
//
#include <hip/hip_runtime.h>
#include <hip/hip_bf16.h>

// GraphSAGE 2-layer forward, MI355X.
// R2: CSR-by-dst built on device (histogram -> scan -> fill), atomic-free
//     mean-aggregation gather (1 wave/node, fused 1/deg normalize).
// Layer1: agg1 = mean_{src->dst} x[src];  h = relu([agg1|x] @ [W1l;W1r] + b1)
// Layer2: hp = h@W2l (project BEFORE aggregating), out = mean(hp) + b2 + h@W2r

#define N_NODES 50000
#define IN_C    128
#define HID_C   256
#define OUT_C   128
#define N_EDGES 600000

#define BM 64
#define BN 64
#define BK 32

// ---------------- CSR build ----------------

__global__ void count_deg(const int* __restrict__ dst, int* __restrict__ cnt, int E) {
    int e = blockIdx.x * blockDim.x + threadIdx.x;
    if (e < E) atomicAdd(&cnt[dst[e]], 1);
}

#define SCAN_B 512
// per-block exclusive scan; block totals to bsums
__global__ __launch_bounds__(SCAN_B) void scan_block(const int* __restrict__ in,
                                                     int* __restrict__ out,
                                                     int* __restrict__ bsums, int n) {
    __shared__ int tmp[SCAN_B];
    int t = threadIdx.x, g = blockIdx.x * SCAN_B + t;
    int v = (g < n) ? in[g] : 0;
    tmp[t] = v; __syncthreads();
    for (int off = 1; off < SCAN_B; off <<= 1) {
        int u = (t >= off) ? tmp[t - off] : 0;
        __syncthreads();
        tmp[t] += u;
        __syncthreads();
    }
    if (g < n) out[g] = tmp[t] - v;          // exclusive
    if (t == SCAN_B - 1) bsums[blockIdx.x] = tmp[t];
}

// single block exclusive scan of up to 128 block sums (in place)
__global__ __launch_bounds__(128) void scan_small(int* __restrict__ data, int n) {
    __shared__ int tmp[128];
    int t = threadIdx.x;
    int v = (t < n) ? data[t] : 0;
    tmp[t] = v; __syncthreads();
    for (int off = 1; off < 128; off <<= 1) {
        int u = (t >= off) ? tmp[t - off] : 0;
        __syncthreads();
        tmp[t] += u;
        __syncthreads();
    }
    if (t < n) data[t] = tmp[t] - v;
}

__global__ __launch_bounds__(SCAN_B) void scan_add(int* __restrict__ out,
                                                   const int* __restrict__ bsums, int n) {
    int g = blockIdx.x * SCAN_B + threadIdx.x;
    if (g < n) out[g] += bsums[blockIdx.x];
}

__global__ void fill_csr(const int* __restrict__ srcI, const int* __restrict__ dstI,
                         const int* __restrict__ row_ptr, int* __restrict__ cursor,
                         int* __restrict__ col, int E) {
    int e = blockIdx.x * blockDim.x + threadIdx.x;
    if (e < E) {
        int d = dstI[e];
        int pos = row_ptr[d] + atomicAdd(&cursor[d], 1);
        col[pos] = srcI[e];
    }
}

// ---------------- mean aggregation (atomic-free gather) ----------------
// 1 wave per node, lane handles 2 channels (128 ch / 64 lanes); 4 nodes/block.
__global__ __launch_bounds__(256) void aggregate_mean128(
    const float* __restrict__ feat, const int* __restrict__ row_ptr,
    const int* __restrict__ deg, const int* __restrict__ col,
    float* __restrict__ outv, int nNodes) {
    int node = blockIdx.x * 4 + (threadIdx.x >> 6);
    int lane = threadIdx.x & 63;
    if (node >= nNodes) return;
    int beg = row_ptr[node];
    int d   = deg[node];
    const float* base = feat + lane * 2;
    float ax = 0.f, ay = 0.f;
    int j = 0;
    for (; j + 2 <= d; j += 2) {            // 2-deep to keep 2 gathers in flight
        int s0 = col[beg + j];
        int s1 = col[beg + j + 1];
        float2 v0 = *(const float2*)(base + (size_t)s0 * 128);
        float2 v1 = *(const float2*)(base + (size_t)s1 * 128);
        ax += v0.x + v1.x; ay += v0.y + v1.y;
    }
    if (j < d) {
        int s = col[beg + j];
        float2 v = *(const float2*)(base + (size_t)s * 128);
        ax += v.x; ay += v.y;
    }
    float inv = 1.f / (float)max(d, 1);
    *(float2*)(outv + (size_t)node * 128 + lane * 2) = make_float2(ax * inv, ay * inv);
}

// ---------------- GEMM ----------------
// C[M,N] = [A0 | A1] @ [B0 ; B1] (+ bias) (+ addend) (relu?)
__global__ __launch_bounds__(256) void sage_gemm(
    const float* __restrict__ A0, const float* __restrict__ B0, int k0,
    const float* __restrict__ A1, const float* __restrict__ B1, int k1,
    const float* __restrict__ bias, const float* __restrict__ addend,
    float* __restrict__ Cout, int M, int N, int relu) {
    const int K = k0 + k1;
    __shared__ float As[BK][BM + 4];
    __shared__ float Bs[BK][BN + 4];

    int tid = threadIdx.x;
    int tx = tid & 15;
    int ty = tid >> 4;
    int mb = blockIdx.x * BM;
    int nb = blockIdx.y * BN;

    int a_row = tid >> 2;
    int a_kc  = (tid & 3) * 8;
    int b_kr = tid >> 3;
    int b_nc = (tid & 7) * 8;

    float acc[4][4] = {{0.f}};

    for (int kt = 0; kt < K; kt += BK) {
        int gm = mb + a_row;
        #pragma unroll
        for (int hh = 0; hh < 2; ++hh) {
            int kk = a_kc + hh * 4;
            int gk = kt + kk;
            float4 v = make_float4(0.f, 0.f, 0.f, 0.f);
            if (gm < M) {
                if (gk < k0) v = *(const float4*)(A0 + (size_t)gm * k0 + gk);
                else         v = *(const float4*)(A1 + (size_t)gm * k1 + (gk - k0));
            }
            As[kk + 0][a_row] = v.x;
            As[kk + 1][a_row] = v.y;
            As[kk + 2][a_row] = v.z;
            As[kk + 3][a_row] = v.w;
        }
        #pragma unroll
        for (int hh = 0; hh < 2; ++hh) {
            int nn = b_nc + hh * 4;
            int gk = kt + b_kr;
            float4 v;
            if (gk < k0) v = *(const float4*)(B0 + (size_t)gk * N + nb + nn);
            else         v = *(const float4*)(B1 + (size_t)(gk - k0) * N + nb + nn);
            *(float4*)&Bs[b_kr][nn] = v;
        }
        __syncthreads();

        #pragma unroll
        for (int k = 0; k < BK; ++k) {
            float a[4], b[4];
            *(float4*)a = *(const float4*)&As[k][ty * 4];
            *(float4*)b = *(const float4*)&Bs[k][tx * 4];
            #pragma unroll
            for (int i = 0; i < 4; ++i)
                #pragma unroll
                for (int j = 0; j < 4; ++j)
                    acc[i][j] = fmaf(a[i], b[j], acc[i][j]);
        }
        __syncthreads();
    }

    #pragma unroll
    for (int i = 0; i < 4; ++i) {
        int gm = mb + ty * 4 + i;
        if (gm >= M) continue;
        #pragma unroll
        for (int j = 0; j < 4; ++j) {
            int gn = nb + tx * 4 + j;
            float v = acc[i][j];
            if (bias)   v += bias[gn];
            if (addend) v += addend[(size_t)gm * N + gn];
            if (relu)   v = fmaxf(v, 0.f);
            Cout[(size_t)gm * N + gn] = v;
        }
    }
}

extern "C" void kernel_launch(void* const* d_in, const int* in_sizes, int n_in,
                              void* d_out, int out_size, void* d_ws, size_t ws_size,
                              hipStream_t stream) {
    const float* x    = (const float*)d_in[0];
    const int*   ei   = (const int*)d_in[1];
    const float* W1l  = (const float*)d_in[2];
    const float* b1   = (const float*)d_in[3];
    const float* W1r  = (const float*)d_in[4];
    const float* W2l  = (const float*)d_in[5];
    const float* b2   = (const float*)d_in[6];
    const float* W2r  = (const float*)d_in[7];
    float* out = (float*)d_out;

    const int E = N_EDGES;
    const int N = N_NODES;
    const int* srcI = ei;
    const int* dstI = ei + E;

    // workspace layout (bytes)
    char* w = (char*)d_ws;
    int*   cnt     = (int*)(w + 0);              // 200000 B
    int*   row_ptr = (int*)(w + 204800);         // 200000 B
    int*   col     = (int*)(w + 409600);         // 2400000 B
    float* agg     = (float*)(w + 2809856);      // 25.6 MB (layer1 agg, reused layer2)
    float* h       = (float*)(w + 28409856);     // 51.2 MB
    float* hp      = (float*)(w + 79609856);     // 25.6 MB
    // transient aliases inside agg region (dead before aggregate writes agg):
    int*   cursor  = (int*)agg;                  // 200000 B
    int*   bsums   = (int*)(w + 2809856 + (4 << 20)); // 512 B, scan block sums

    const int nScanBlocks = (N + SCAN_B - 1) / SCAN_B;   // 98

    // ---- CSR build ----
    hipMemsetAsync(cnt, 0, N * sizeof(int), stream);
    hipMemsetAsync(cursor, 0, N * sizeof(int), stream);
    count_deg<<<(E + 255) / 256, 256, 0, stream>>>(dstI, cnt, E);
    scan_block<<<nScanBlocks, SCAN_B, 0, stream>>>(cnt, row_ptr, bsums, N);
    scan_small<<<1, 128, 0, stream>>>(bsums, nScanBlocks);
    scan_add<<<nScanBlocks, SCAN_B, 0, stream>>>(row_ptr, bsums, N);
    fill_csr<<<(E + 255) / 256, 256, 0, stream>>>(srcI, dstI, row_ptr, cursor, col, E);

    // ---- layer 1 ----
    aggregate_mean128<<<(N + 3) / 4, 256, 0, stream>>>(x, row_ptr, cnt, col, agg, N);
    {
        dim3 grid((N + BM - 1) / BM, HID_C / BN);
        sage_gemm<<<grid, 256, 0, stream>>>(agg, W1l, IN_C, x, W1r, IN_C,
                                            b1, nullptr, h, N, HID_C, 1);
    }

    // ---- layer 2: project first, then aggregate 128-wide ----
    {
        dim3 grid((N + BM - 1) / BM, OUT_C / BN);
        sage_gemm<<<grid, 256, 0, stream>>>(h, W2l, HID_C, nullptr, nullptr, 0,
                                            nullptr, nullptr, hp, N, OUT_C, 0);
    }
    aggregate_mean128<<<(N + 3) / 4, 256, 0, stream>>>(hp, row_ptr, cnt, col, agg, N);
    {
        dim3 grid((N + BM - 1) / BM, OUT_C / BN);
        sage_gemm<<<grid, 256, 0, stream>>>(h, W2r, HID_C, nullptr, nullptr, 0,
                                            b2, agg, out, N, OUT_C, 0);
    }
}

// Round 3
// 313.476 us; speedup vs baseline: 7.5541x; 1.4677x over previous
//
#include <hip/hip_runtime.h>
#include <hip/hip_bf16.h>

// GraphSAGE 2-layer forward, MI355X. R3: bf16 MFMA GEMMs + bf16 gathers.
// Layer1: agg1 = mean x[src]; h = relu([agg1|x] @ [W1l;W1r] + b1)   (bf16 MFMA)
// Layer2: hp = h@W2l (project before aggregate), out = mean(hp) + b2 + h@W2r

#define N_NODES 50000
#define IN_C    128
#define HID_C   256
#define OUT_C   128
#define N_EDGES 600000

typedef __attribute__((ext_vector_type(8))) short short8;   // 8 bf16 (4 VGPR)
typedef __attribute__((ext_vector_type(4))) float f32x4;

// ---------------- CSR build ----------------

__global__ void count_deg(const int* __restrict__ dst, int* __restrict__ cnt, int E) {
    int e = blockIdx.x * blockDim.x + threadIdx.x;
    if (e < E) atomicAdd(&cnt[dst[e]], 1);
}

#define SCAN_B 512
__global__ __launch_bounds__(SCAN_B) void scan_block(const int* __restrict__ in,
                                                     int* __restrict__ out,
                                                     int* __restrict__ bsums, int n) {
    __shared__ int tmp[SCAN_B];
    int t = threadIdx.x, g = blockIdx.x * SCAN_B + t;
    int v = (g < n) ? in[g] : 0;
    tmp[t] = v; __syncthreads();
    for (int off = 1; off < SCAN_B; off <<= 1) {
        int u = (t >= off) ? tmp[t - off] : 0;
        __syncthreads();
        tmp[t] += u;
        __syncthreads();
    }
    if (g < n) out[g] = tmp[t] - v;
    if (t == SCAN_B - 1) bsums[blockIdx.x] = tmp[t];
}

__global__ __launch_bounds__(128) void scan_small(int* __restrict__ data, int n) {
    __shared__ int tmp[128];
    int t = threadIdx.x;
    int v = (t < n) ? data[t] : 0;
    tmp[t] = v; __syncthreads();
    for (int off = 1; off < 128; off <<= 1) {
        int u = (t >= off) ? tmp[t - off] : 0;
        __syncthreads();
        tmp[t] += u;
        __syncthreads();
    }
    if (t < n) data[t] = tmp[t] - v;
}

__global__ __launch_bounds__(SCAN_B) void scan_add(int* __restrict__ out,
                                                   const int* __restrict__ bsums, int n) {
    int g = blockIdx.x * SCAN_B + threadIdx.x;
    if (g < n) out[g] += bsums[blockIdx.x];
}

__global__ void fill_csr(const int* __restrict__ srcI, const int* __restrict__ dstI,
                         const int* __restrict__ row_ptr, int* __restrict__ cursor,
                         int* __restrict__ col, int E) {
    int e = blockIdx.x * blockDim.x + threadIdx.x;
    if (e < E) {
        int d = dstI[e];
        int pos = row_ptr[d] + atomicAdd(&cursor[d], 1);
        col[pos] = srcI[e];
    }
}

// ---------------- conversions ----------------

// dst[n*dstStride + k] = bf16(src[k*N + n])  (reads coalesced over n)
__global__ void transpose_cvt(const float* __restrict__ src, __hip_bfloat16* __restrict__ dst,
                              int K, int N, int dstStride) {
    int t = blockIdx.x * blockDim.x + threadIdx.x;
    if (t >= K * N) return;
    int k = t / N, n = t - k * N;
    dst[(size_t)n * dstStride + k] = __float2bfloat16(src[t]);
}

// x [50000,128] fp32 -> A1 cols 128..255 bf16 (A1 row stride 256)
__global__ void cvt_x_to_A1(const float* __restrict__ x, __hip_bfloat16* __restrict__ A1, int n) {
    int t = blockIdx.x * blockDim.x + threadIdx.x;
    if (t >= n) return;
    int row = t >> 5, c = (t & 31) * 4;
    float4 v = *(const float4*)(x + (size_t)row * 128 + c);
    __hip_bfloat16* d = A1 + (size_t)row * 256 + 128 + c;
    __hip_bfloat162 p0, p1;
    p0.x = __float2bfloat16(v.x); p0.y = __float2bfloat16(v.y);
    p1.x = __float2bfloat16(v.z); p1.y = __float2bfloat16(v.w);
    *(__hip_bfloat162*)d = p0;
    *(__hip_bfloat162*)(d + 2) = p1;
}

// ---------------- mean aggregation (bf16 gather, fp32 accum) ----------------
// 1 wave/node, lane handles 2 channels (bf162). OUT_BF16: write bf162, else float2.
template <int OUT_BF16>
__global__ __launch_bounds__(256) void aggregate_mean(
    const __hip_bfloat162* __restrict__ feat, int featStride2,
    const int* __restrict__ row_ptr, const int* __restrict__ deg,
    const int* __restrict__ col, void* __restrict__ outp, int outStride2, int nNodes) {
    int node = blockIdx.x * 4 + (threadIdx.x >> 6);
    int lane = threadIdx.x & 63;
    if (node >= nNodes) return;
    int beg = row_ptr[node];
    int d   = deg[node];
    const __hip_bfloat162* base = feat + lane;
    float ax = 0.f, ay = 0.f;
    int j = 0;
    for (; j + 2 <= d; j += 2) {
        int s0 = col[beg + j];
        int s1 = col[beg + j + 1];
        __hip_bfloat162 v0 = base[(size_t)s0 * featStride2];
        __hip_bfloat162 v1 = base[(size_t)s1 * featStride2];
        ax += __bfloat162float(v0.x) + __bfloat162float(v1.x);
        ay += __bfloat162float(v0.y) + __bfloat162float(v1.y);
    }
    if (j < d) {
        __hip_bfloat162 v = base[(size_t)col[beg + j] * featStride2];
        ax += __bfloat162float(v.x);
        ay += __bfloat162float(v.y);
    }
    float inv = 1.f / (float)max(d, 1);
    ax *= inv; ay *= inv;
    if (OUT_BF16) {
        __hip_bfloat162 o;
        o.x = __float2bfloat16(ax); o.y = __float2bfloat16(ay);
        ((__hip_bfloat162*)outp)[(size_t)node * outStride2 + lane] = o;
    } else {
        ((float2*)outp)[(size_t)node * outStride2 + lane] = make_float2(ax, ay);
    }
}

// ---------------- bf16 MFMA GEMM ----------------
// C[M,N] = A[M,K](row-major, lda) @ Bt[N,K]^T (+bias) (+addend fp32) (relu?)
// 128x128 tile, BK=64, global_load_lds width=16, XOR chunk swizzle in LDS.

#define GBM 128
#define GBN 128
#define GBK 64

__device__ __forceinline__ void gload16(const void* g, void* l) {
    typedef const __attribute__((address_space(1))) unsigned int* gp_t;
    typedef __attribute__((address_space(3))) unsigned int* lp_t;
    __builtin_amdgcn_global_load_lds((gp_t)g, (lp_t)l, 16, 0, 0);
}

__global__ __launch_bounds__(256) void gemm_mfma(
    const __hip_bfloat16* __restrict__ A, int lda,
    const __hip_bfloat16* __restrict__ Bt,            // [N][K] row-major, ld=K
    const float* __restrict__ bias,
    const float* __restrict__ addend,                 // [M][N] fp32 or null
    void* __restrict__ Cc, int c_bf16,
    int M, int N, int K, int relu) {
    __shared__ __hip_bfloat16 Als[GBM * GBK];         // [128][64] row-major, 16 KB
    __shared__ __hip_bfloat16 Bls[GBN * GBK];         // [128][64] row-major, 16 KB

    int tid  = threadIdx.x;
    int wave = tid >> 6, lane = tid & 63;
    int wm = wave >> 1, wn = wave & 1;
    int mb = blockIdx.x * GBM, nb = blockIdx.y * GBN;

    // staging map: this thread's row-within-32-row wave slice
    int srow_base = wave * 32;                 // wave covers 32 rows via 4 instrs x 8 rows
    int lrow = lane >> 3;                      // 0..7 within 8-row group
    int pch  = lane & 7;                       // physical 16B chunk within row

    f32x4 acc[4][4];
    #pragma unroll
    for (int i = 0; i < 4; ++i)
        #pragma unroll
        for (int j = 0; j < 4; ++j)
            acc[i][j] = (f32x4){0.f, 0.f, 0.f, 0.f};

    for (int kt = 0; kt < K; kt += GBK) {
        #pragma unroll
        for (int t = 0; t < 4; ++t) {
            int rloc = srow_base + t * 8 + lrow;
            int lch  = pch ^ (rloc & 7);       // logical chunk this lane fetches
            // A row (clamped for M tail)
            int ga_row = mb + rloc; if (ga_row >= M) ga_row = M - 1;
            const __hip_bfloat16* ga = A + (size_t)ga_row * lda + kt + lch * 8;
            gload16(ga, &Als[(srow_base + t * 8) * GBK]);
            // B^T row (N is a multiple of 128 here)
            const __hip_bfloat16* gb = Bt + (size_t)(nb + rloc) * K + kt + lch * 8;
            gload16(gb, &Bls[(srow_base + t * 8) * GBK]);
        }
        __syncthreads();

        #pragma unroll
        for (int ks = 0; ks < GBK; ks += 32) {
            int chunkL = (ks >> 3) + (lane >> 4);   // logical chunk 0..7
            short8 af[4], bf[4];
            #pragma unroll
            for (int i = 0; i < 4; ++i) {
                int row = wm * 64 + i * 16 + (lane & 15);
                int pc  = chunkL ^ (row & 7);
                af[i] = *(const short8*)&Als[row * GBK + pc * 8];
            }
            #pragma unroll
            for (int j = 0; j < 4; ++j) {
                int row = wn * 64 + j * 16 + (lane & 15);
                int pc  = chunkL ^ (row & 7);
                bf[j] = *(const short8*)&Bls[row * GBK + pc * 8];
            }
            #pragma unroll
            for (int i = 0; i < 4; ++i)
                #pragma unroll
                for (int j = 0; j < 4; ++j)
                    acc[i][j] = __builtin_amdgcn_mfma_f32_16x16x32_bf16(
                        af[i], bf[j], acc[i][j], 0, 0, 0);
        }
        __syncthreads();
    }

    // epilogue: C/D layout col=lane&15, row=(lane>>4)*4+reg
    float bcol[4];
    int coln[4];
    #pragma unroll
    for (int j = 0; j < 4; ++j) {
        coln[j] = nb + wn * 64 + j * 16 + (lane & 15);
        bcol[j] = bias ? bias[coln[j]] : 0.f;
    }
    #pragma unroll
    for (int i = 0; i < 4; ++i) {
        #pragma unroll
        for (int r = 0; r < 4; ++r) {
            int row = mb + wm * 64 + i * 16 + (lane >> 4) * 4 + r;
            if (row >= M) continue;
            #pragma unroll
            for (int j = 0; j < 4; ++j) {
                float v = acc[i][j][r] + bcol[j];
                if (addend) v += addend[(size_t)row * N + coln[j]];
                if (relu)   v = fmaxf(v, 0.f);
                if (c_bf16) ((__hip_bfloat16*)Cc)[(size_t)row * N + coln[j]] = __float2bfloat16(v);
                else        ((float*)Cc)[(size_t)row * N + coln[j]] = v;
            }
        }
    }
}

extern "C" void kernel_launch(void* const* d_in, const int* in_sizes, int n_in,
                              void* d_out, int out_size, void* d_ws, size_t ws_size,
                              hipStream_t stream) {
    const float* x    = (const float*)d_in[0];
    const int*   ei   = (const int*)d_in[1];
    const float* W1l  = (const float*)d_in[2];   // [128,256]
    const float* b1   = (const float*)d_in[3];
    const float* W1r  = (const float*)d_in[4];   // [128,256]
    const float* W2l  = (const float*)d_in[5];   // [256,128]
    const float* b2   = (const float*)d_in[6];
    const float* W2r  = (const float*)d_in[7];   // [256,128]
    float* out = (float*)d_out;

    const int E = N_EDGES;
    const int N = N_NODES;
    const int* srcI = ei;
    const int* dstI = ei + E;

    // workspace layout (bytes)
    char* w = (char*)d_ws;
    int*            cnt     = (int*)(w + 0);             // 200000
    int*            row_ptr = (int*)(w + 204800);        // 200000
    int*            col     = (int*)(w + 409600);        // 2400000
    int*            bsums   = (int*)(w + 2809856);       // 512
    __hip_bfloat16* W1t     = (__hip_bfloat16*)(w + 2818048);  // [256][256] 131072
    __hip_bfloat16* W2lt    = (__hip_bfloat16*)(w + 2949120);  // [128][256] 65536
    __hip_bfloat16* W2rt    = (__hip_bfloat16*)(w + 3014656);  // [128][256] 65536
    int*            cursor  = (int*)(w + 3080192);       // 200000
    __hip_bfloat16* A1      = (__hip_bfloat16*)(w + 3280896);  // [50000][256] 25.6 MB
    __hip_bfloat16* h_bf    = (__hip_bfloat16*)(w + 28880896); // [50000][256] 25.6 MB
    __hip_bfloat16* hp_bf   = (__hip_bfloat16*)(w + 54480896); // [50000][128] 12.8 MB
    float*          agg2    = (float*)(w + 67280896);    // [50000][128] fp32 25.6 MB

    const int nScanBlocks = (N + SCAN_B - 1) / SCAN_B;   // 98

    // ---- CSR build ----
    hipMemsetAsync(cnt, 0, N * sizeof(int), stream);
    hipMemsetAsync(cursor, 0, N * sizeof(int), stream);
    count_deg<<<(E + 255) / 256, 256, 0, stream>>>(dstI, cnt, E);
    scan_block<<<nScanBlocks, SCAN_B, 0, stream>>>(cnt, row_ptr, bsums, N);
    scan_small<<<1, 128, 0, stream>>>(bsums, nScanBlocks);
    scan_add<<<nScanBlocks, SCAN_B, 0, stream>>>(row_ptr, bsums, N);
    fill_csr<<<(E + 255) / 256, 256, 0, stream>>>(srcI, dstI, row_ptr, cursor, col, E);

    // ---- weight transpose+cvt (tiny) ----
    transpose_cvt<<<128, 256, 0, stream>>>(W1l, W1t,        128, 256, 256);
    transpose_cvt<<<128, 256, 0, stream>>>(W1r, W1t + 128,  128, 256, 256);
    transpose_cvt<<<128, 256, 0, stream>>>(W2l, W2lt,       256, 128, 256);
    transpose_cvt<<<128, 256, 0, stream>>>(W2r, W2rt,       256, 128, 256);

    // ---- x -> bf16 (A1 cols 128..255) ----
    cvt_x_to_A1<<<(N * 32 + 255) / 256, 256, 0, stream>>>(x, A1, N * 32);

    // ---- layer 1 ----
    aggregate_mean<1><<<(N + 3) / 4, 256, 0, stream>>>(
        (const __hip_bfloat162*)(A1 + 128), 128, row_ptr, cnt, col,
        (void*)A1, 128, N);
    {
        dim3 grid((N + GBM - 1) / GBM, HID_C / GBN);
        gemm_mfma<<<grid, 256, 0, stream>>>(A1, 256, W1t, b1, nullptr,
                                            (void*)h_bf, 1, N, HID_C, 256, 1);
    }

    // ---- layer 2: project first, then aggregate 128-wide ----
    {
        dim3 grid((N + GBM - 1) / GBM, OUT_C / GBN);
        gemm_mfma<<<grid, 256, 0, stream>>>(h_bf, 256, W2lt, nullptr, nullptr,
                                            (void*)hp_bf, 1, N, OUT_C, 256, 0);
    }
    aggregate_mean<0><<<(N + 3) / 4, 256, 0, stream>>>(
        (const __hip_bfloat162*)hp_bf, 64, row_ptr, cnt, col,
        (void*)agg2, 64, N);
    {
        dim3 grid((N + GBM - 1) / GBM, OUT_C / GBN);
        gemm_mfma<<<grid, 256, 0, stream>>>(h_bf, 256, W2rt, b2, agg2,
                                            (void*)out, 0, N, OUT_C, 256, 0);
    }
}

// Round 4
// 258.812 us; speedup vs baseline: 9.1496x; 1.2112x over previous
//
#include <hip/hip_runtime.h>
#include <hip/hip_bf16.h>

// GraphSAGE 2-layer forward, MI355X. R4:
//  - aggregation: 2 nodes/wave (32 lanes x 8B bf16x4 loads), 4-deep unroll
//    -> 8 outstanding gathers per wave (was 2x4B).
//  - layer-2 GEMMs fused into one N=256 pass over h (y==0 -> hp bf16,
//    y==1 -> pre = h@W2r + b2 fp32); final aggregate does out = pre + mean(hp).
//  - scan_add dual-writes cursor (drops a memset).

#define N_NODES 50000
#define IN_C    128
#define HID_C   256
#define OUT_C   128
#define N_EDGES 600000

typedef __attribute__((ext_vector_type(8))) short short8;   // 8 bf16
typedef __attribute__((ext_vector_type(4))) short bf16x4;   // 4 bf16 (8 B)
typedef __attribute__((ext_vector_type(4))) float f32x4;

__device__ __forceinline__ float bf2f(short s) {
    union { unsigned u; float f; } c;
    c.u = ((unsigned)(unsigned short)s) << 16;
    return c.f;
}

// ---------------- CSR build ----------------

__global__ void count_deg(const int* __restrict__ dst, int* __restrict__ cnt, int E) {
    int e = blockIdx.x * blockDim.x + threadIdx.x;
    if (e < E) atomicAdd(&cnt[dst[e]], 1);
}

#define SCAN_B 512
__global__ __launch_bounds__(SCAN_B) void scan_block(const int* __restrict__ in,
                                                     int* __restrict__ out,
                                                     int* __restrict__ bsums, int n) {
    __shared__ int tmp[SCAN_B];
    int t = threadIdx.x, g = blockIdx.x * SCAN_B + t;
    int v = (g < n) ? in[g] : 0;
    tmp[t] = v; __syncthreads();
    for (int off = 1; off < SCAN_B; off <<= 1) {
        int u = (t >= off) ? tmp[t - off] : 0;
        __syncthreads();
        tmp[t] += u;
        __syncthreads();
    }
    if (g < n) out[g] = tmp[t] - v;
    if (t == SCAN_B - 1) bsums[blockIdx.x] = tmp[t];
}

__global__ __launch_bounds__(128) void scan_small(int* __restrict__ data, int n) {
    __shared__ int tmp[128];
    int t = threadIdx.x;
    int v = (t < n) ? data[t] : 0;
    tmp[t] = v; __syncthreads();
    for (int off = 1; off < 128; off <<= 1) {
        int u = (t >= off) ? tmp[t - off] : 0;
        __syncthreads();
        tmp[t] += u;
        __syncthreads();
    }
    if (t < n) data[t] = tmp[t] - v;
}

// adds block offsets; also writes cursor=row_ptr so fill_csr needs no memset
__global__ __launch_bounds__(SCAN_B) void scan_add(int* __restrict__ out,
                                                   int* __restrict__ cursor,
                                                   const int* __restrict__ bsums, int n) {
    int g = blockIdx.x * SCAN_B + threadIdx.x;
    if (g < n) {
        int v = out[g] + bsums[blockIdx.x];
        out[g] = v;
        cursor[g] = v;
    }
}

// cursor holds absolute write position (pre-initialized to row_ptr)
__global__ void fill_csr(const int* __restrict__ srcI, const int* __restrict__ dstI,
                         int* __restrict__ cursor, int* __restrict__ col, int E) {
    int e = blockIdx.x * blockDim.x + threadIdx.x;
    if (e < E) {
        int pos = atomicAdd(&cursor[dstI[e]], 1);
        col[pos] = srcI[e];
    }
}

// ---------------- conversions ----------------

// dst[n*dstStride + k] = bf16(src[k*N + n])
__global__ void transpose_cvt(const float* __restrict__ src, __hip_bfloat16* __restrict__ dst,
                              int K, int N, int dstStride) {
    int t = blockIdx.x * blockDim.x + threadIdx.x;
    if (t >= K * N) return;
    int k = t / N, n = t - k * N;
    dst[(size_t)n * dstStride + k] = __float2bfloat16(src[t]);
}

// x [50000,128] fp32 -> A1 cols 128..255 bf16 (row stride 256)
__global__ void cvt_x_to_A1(const float* __restrict__ x, __hip_bfloat16* __restrict__ A1, int n) {
    int t = blockIdx.x * blockDim.x + threadIdx.x;
    if (t >= n) return;
    int row = t >> 5, c = (t & 31) * 4;
    float4 v = *(const float4*)(x + (size_t)row * 128 + c);
    __hip_bfloat16* d = A1 + (size_t)row * 256 + 128 + c;
    __hip_bfloat162 p0, p1;
    p0.x = __float2bfloat16(v.x); p0.y = __float2bfloat16(v.y);
    p1.x = __float2bfloat16(v.z); p1.y = __float2bfloat16(v.w);
    *(__hip_bfloat162*)d = p0;
    *(__hip_bfloat162*)(d + 2) = p1;
}

// ---------------- mean aggregation ----------------
// 32 lanes per node (lane covers 4 ch via one 8B load), 2 nodes/wave,
// 8 nodes/block, 4-deep unroll -> up to 8 outstanding gathers per wave.
// FINAL=0: write bf16 (8B) to outp (stride outStride elems).
// FINAL=1: write fp32 out = pre + mean (16B), stride 128.
template <int FINAL>
__global__ __launch_bounds__(256) void aggregate_mean(
    const __hip_bfloat16* __restrict__ feat, int featStride,
    const int* __restrict__ row_ptr, const int* __restrict__ deg,
    const int* __restrict__ col,
    void* __restrict__ outp, int outStride,
    const float* __restrict__ pre, int nNodes) {
    int node = blockIdx.x * 8 + (threadIdx.x >> 5);
    int sl   = threadIdx.x & 31;
    if (node >= nNodes) return;
    int beg = row_ptr[node];
    int d   = deg[node];
    const __hip_bfloat16* base = feat + sl * 4;
    float a0 = 0.f, a1 = 0.f, a2 = 0.f, a3 = 0.f;
    int j = 0;
    for (; j + 4 <= d; j += 4) {
        int s0 = col[beg + j];
        int s1 = col[beg + j + 1];
        int s2 = col[beg + j + 2];
        int s3 = col[beg + j + 3];
        bf16x4 v0 = *(const bf16x4*)(base + (size_t)s0 * featStride);
        bf16x4 v1 = *(const bf16x4*)(base + (size_t)s1 * featStride);
        bf16x4 v2 = *(const bf16x4*)(base + (size_t)s2 * featStride);
        bf16x4 v3 = *(const bf16x4*)(base + (size_t)s3 * featStride);
        a0 += (bf2f(v0.x) + bf2f(v1.x)) + (bf2f(v2.x) + bf2f(v3.x));
        a1 += (bf2f(v0.y) + bf2f(v1.y)) + (bf2f(v2.y) + bf2f(v3.y));
        a2 += (bf2f(v0.z) + bf2f(v1.z)) + (bf2f(v2.z) + bf2f(v3.z));
        a3 += (bf2f(v0.w) + bf2f(v1.w)) + (bf2f(v2.w) + bf2f(v3.w));
    }
    for (; j < d; ++j) {
        bf16x4 v = *(const bf16x4*)(base + (size_t)col[beg + j] * featStride);
        a0 += bf2f(v.x); a1 += bf2f(v.y); a2 += bf2f(v.z); a3 += bf2f(v.w);
    }
    float inv = 1.f / (float)max(d, 1);
    a0 *= inv; a1 *= inv; a2 *= inv; a3 *= inv;
    if (FINAL) {
        const float4 p = *(const float4*)(pre + (size_t)node * 128 + sl * 4);
        float4 o = make_float4(a0 + p.x, a1 + p.y, a2 + p.z, a3 + p.w);
        *(float4*)((float*)outp + (size_t)node * 128 + sl * 4) = o;
    } else {
        __hip_bfloat16* o = (__hip_bfloat16*)outp + (size_t)node * outStride + sl * 4;
        __hip_bfloat162 q0, q1;
        q0.x = __float2bfloat16(a0); q0.y = __float2bfloat16(a1);
        q1.x = __float2bfloat16(a2); q1.y = __float2bfloat16(a3);
        *(__hip_bfloat162*)o = q0;
        *(__hip_bfloat162*)(o + 2) = q1;
    }
}

// ---------------- bf16 MFMA GEMM ----------------
// 128x128 tile, BK=64, global_load_lds width=16, XOR chunk swizzle.
// mode 0 (layer1): out = relu(A@Bt^T + bias) -> outBf[row*outBfStride+col]
// mode 1 (layer2 fused, grid.y=2):
//   y==0: outBf[row*128+col]   = bf16(A@W2l^T)          (cols 0..127 of Bt)
//   y==1: outF [row*128+col']  = A@W2r^T + bias[col']   (cols 128..255, col'=col-128)

#define GBM 128
#define GBN 128
#define GBK 64

__device__ __forceinline__ void gload16(const void* g, void* l) {
    typedef const __attribute__((address_space(1))) unsigned int* gp_t;
    typedef __attribute__((address_space(3))) unsigned int* lp_t;
    __builtin_amdgcn_global_load_lds((gp_t)g, (lp_t)l, 16, 0, 0);
}

__global__ __launch_bounds__(256) void gemm_mfma(
    const __hip_bfloat16* __restrict__ A, int lda,
    const __hip_bfloat16* __restrict__ Bt,    // [Ntot][K] row-major, ld=K
    const float* __restrict__ bias,
    __hip_bfloat16* __restrict__ outBf, int outBfStride,
    float* __restrict__ outF,
    int M, int K, int mode) {
    __shared__ __hip_bfloat16 Als[GBM * GBK];
    __shared__ __hip_bfloat16 Bls[GBN * GBK];

    int tid  = threadIdx.x;
    int wave = tid >> 6, lane = tid & 63;
    int wm = wave >> 1, wn = wave & 1;
    int mb = blockIdx.x * GBM, nb = blockIdx.y * GBN;

    int srow_base = wave * 32;
    int lrow = lane >> 3;
    int pch  = lane & 7;

    f32x4 acc[4][4];
    #pragma unroll
    for (int i = 0; i < 4; ++i)
        #pragma unroll
        for (int j = 0; j < 4; ++j)
            acc[i][j] = (f32x4){0.f, 0.f, 0.f, 0.f};

    for (int kt = 0; kt < K; kt += GBK) {
        #pragma unroll
        for (int t = 0; t < 4; ++t) {
            int rloc = srow_base + t * 8 + lrow;
            int lch  = pch ^ (rloc & 7);
            int ga_row = mb + rloc; if (ga_row >= M) ga_row = M - 1;
            const __hip_bfloat16* ga = A + (size_t)ga_row * lda + kt + lch * 8;
            gload16(ga, &Als[(srow_base + t * 8) * GBK]);
            const __hip_bfloat16* gb = Bt + (size_t)(nb + rloc) * K + kt + lch * 8;
            gload16(gb, &Bls[(srow_base + t * 8) * GBK]);
        }
        __syncthreads();

        #pragma unroll
        for (int ks = 0; ks < GBK; ks += 32) {
            int chunkL = (ks >> 3) + (lane >> 4);
            short8 af[4], bf[4];
            #pragma unroll
            for (int i = 0; i < 4; ++i) {
                int row = wm * 64 + i * 16 + (lane & 15);
                int pc  = chunkL ^ (row & 7);
                af[i] = *(const short8*)&Als[row * GBK + pc * 8];
            }
            #pragma unroll
            for (int j = 0; j < 4; ++j) {
                int row = wn * 64 + j * 16 + (lane & 15);
                int pc  = chunkL ^ (row & 7);
                bf[j] = *(const short8*)&Bls[row * GBK + pc * 8];
            }
            #pragma unroll
            for (int i = 0; i < 4; ++i)
                #pragma unroll
                for (int j = 0; j < 4; ++j)
                    acc[i][j] = __builtin_amdgcn_mfma_f32_16x16x32_bf16(
                        af[i], bf[j], acc[i][j], 0, 0, 0);
        }
        __syncthreads();
    }

    // epilogue: C/D layout col=lane&15, row=(lane>>4)*4+reg
    int cn[4];
    float bc[4];
    #pragma unroll
    for (int j = 0; j < 4; ++j) {
        cn[j] = wn * 64 + j * 16 + (lane & 15);     // col within tile (nb added per-mode)
        bc[j] = 0.f;
    }
    if (mode == 0) {
        #pragma unroll
        for (int j = 0; j < 4; ++j) bc[j] = bias[nb + cn[j]];
        #pragma unroll
        for (int i = 0; i < 4; ++i)
            #pragma unroll
            for (int r = 0; r < 4; ++r) {
                int row = mb + wm * 64 + i * 16 + (lane >> 4) * 4 + r;
                if (row >= M) continue;
                #pragma unroll
                for (int j = 0; j < 4; ++j) {
                    float v = fmaxf(acc[i][j][r] + bc[j], 0.f);
                    outBf[(size_t)row * outBfStride + nb + cn[j]] = __float2bfloat16(v);
                }
            }
    } else if (blockIdx.y == 0) {
        #pragma unroll
        for (int i = 0; i < 4; ++i)
            #pragma unroll
            for (int r = 0; r < 4; ++r) {
                int row = mb + wm * 64 + i * 16 + (lane >> 4) * 4 + r;
                if (row >= M) continue;
                #pragma unroll
                for (int j = 0; j < 4; ++j)
                    outBf[(size_t)row * 128 + cn[j]] = __float2bfloat16(acc[i][j][r]);
            }
    } else {
        #pragma unroll
        for (int j = 0; j < 4; ++j) bc[j] = bias[cn[j]];
        #pragma unroll
        for (int i = 0; i < 4; ++i)
            #pragma unroll
            for (int r = 0; r < 4; ++r) {
                int row = mb + wm * 64 + i * 16 + (lane >> 4) * 4 + r;
                if (row >= M) continue;
                #pragma unroll
                for (int j = 0; j < 4; ++j)
                    outF[(size_t)row * 128 + cn[j]] = acc[i][j][r] + bc[j];
            }
    }
}

extern "C" void kernel_launch(void* const* d_in, const int* in_sizes, int n_in,
                              void* d_out, int out_size, void* d_ws, size_t ws_size,
                              hipStream_t stream) {
    const float* x    = (const float*)d_in[0];
    const int*   ei   = (const int*)d_in[1];
    const float* W1l  = (const float*)d_in[2];   // [128,256]
    const float* b1   = (const float*)d_in[3];
    const float* W1r  = (const float*)d_in[4];   // [128,256]
    const float* W2l  = (const float*)d_in[5];   // [256,128]
    const float* b2   = (const float*)d_in[6];
    const float* W2r  = (const float*)d_in[7];   // [256,128]
    float* out = (float*)d_out;

    const int E = N_EDGES;
    const int N = N_NODES;
    const int* srcI = ei;
    const int* dstI = ei + E;

    // workspace layout (bytes)
    char* w = (char*)d_ws;
    int*            cnt     = (int*)(w + 0);                   // 200000
    int*            row_ptr = (int*)(w + 204800);              // 200000
    int*            col     = (int*)(w + 409600);              // 2400000
    int*            bsums   = (int*)(w + 2809856);             // 512
    __hip_bfloat16* W1t     = (__hip_bfloat16*)(w + 2818048);  // [256][256]
    __hip_bfloat16* W2t     = (__hip_bfloat16*)(w + 2949120);  // [256][256]
    int*            cursor  = (int*)(w + 3080192);             // 200000
    __hip_bfloat16* A1      = (__hip_bfloat16*)(w + 3280896);  // [50000][256]
    __hip_bfloat16* h_bf    = (__hip_bfloat16*)(w + 28880896); // [50000][256]
    __hip_bfloat16* hp_bf   = (__hip_bfloat16*)(w + 54480896); // [50000][128]
    float*          pre     = (float*)(w + 67280896);          // [50000][128] fp32

    const int nScanBlocks = (N + SCAN_B - 1) / SCAN_B;   // 98

    // ---- CSR build ----
    hipMemsetAsync(cnt, 0, N * sizeof(int), stream);
    count_deg<<<(E + 255) / 256, 256, 0, stream>>>(dstI, cnt, E);
    scan_block<<<nScanBlocks, SCAN_B, 0, stream>>>(cnt, row_ptr, bsums, N);
    scan_small<<<1, 128, 0, stream>>>(bsums, nScanBlocks);
    scan_add<<<nScanBlocks, SCAN_B, 0, stream>>>(row_ptr, cursor, bsums, N);
    fill_csr<<<(E + 255) / 256, 256, 0, stream>>>(srcI, dstI, cursor, col, E);

    // ---- weight transpose+cvt ----
    transpose_cvt<<<128, 256, 0, stream>>>(W1l, W1t,             128, 256, 256);
    transpose_cvt<<<128, 256, 0, stream>>>(W1r, W1t + 128,       128, 256, 256);
    transpose_cvt<<<128, 256, 0, stream>>>(W2l, W2t,             256, 128, 256);
    transpose_cvt<<<128, 256, 0, stream>>>(W2r, W2t + 128 * 256, 256, 128, 256);

    // ---- x -> bf16 (A1 cols 128..255) ----
    cvt_x_to_A1<<<(N * 32 + 255) / 256, 256, 0, stream>>>(x, A1, N * 32);

    // ---- layer 1: aggregate then GEMM ----
    aggregate_mean<0><<<(N + 7) / 8, 256, 0, stream>>>(
        A1 + 128, 256, row_ptr, cnt, col, (void*)A1, 256, nullptr, N);
    {
        dim3 grid((N + GBM - 1) / GBM, HID_C / GBN);   // 391 x 2
        gemm_mfma<<<grid, 256, 0, stream>>>(A1, 256, W1t, b1,
                                            h_bf, 256, nullptr, N, 256, 0);
    }

    // ---- layer 2: fused projection (y0 -> hp bf16, y1 -> pre = h@W2r + b2) ----
    {
        dim3 grid((N + GBM - 1) / GBM, 2);
        gemm_mfma<<<grid, 256, 0, stream>>>(h_bf, 256, W2t, b2,
                                            hp_bf, 128, pre, N, 256, 1);
    }
    // ---- final: out = pre + mean(hp) ----
    aggregate_mean<1><<<(N + 7) / 8, 256, 0, stream>>>(
        hp_bf, 128, row_ptr, cnt, col, (void*)out, 128, pre, N);
}

// Round 6
// 245.213 us; speedup vs baseline: 9.6570x; 1.0555x over previous
//
#include <hip/hip_runtime.h>
#include <hip/hip_bf16.h>

// GraphSAGE 2-layer forward, MI355X. R6 (= R5 with prep-partition fix):
//  - 8 launches: prep(zero+transposes+cvt_x), count_deg, assign_offsets,
//    fill_csr, agg1, gemm1, gemm2(fused), agg2.
//  - aggregation: 16 lanes/node x 16B bf16x8 loads, 4 nodes/wave, 4-deep
//    unroll -> 16 outstanding 16B gathers/wave.
//  - R5 BUG FIX: zero-partition was 49 blocks (12544 ints) for a 50000-int
//    cnt array -> poisoned degrees -> OOB col writes -> abort. Now 196.

#define N_NODES 50000
#define IN_C    128
#define HID_C   256
#define OUT_C   128
#define N_EDGES 600000

// prep block partition
#define PB_ZERO 196                  // ceil(50000/256)
#define PB_W1   (PB_ZERO + 256)      // 452
#define PB_W2   (PB_W1 + 256)        // 708
#define PB_X    (PB_W2 + 6250)       // 6958 total

typedef __attribute__((ext_vector_type(8))) short short8;   // 8 bf16 (16B)
typedef __attribute__((ext_vector_type(4))) float f32x4;

__device__ __forceinline__ float bf2f(short s) {
    union { unsigned u; float f; } c;
    c.u = ((unsigned)(unsigned short)s) << 16;
    return c.f;
}

// ---------------- fused prep ----------------
__global__ __launch_bounds__(256) void prep(
    const float* __restrict__ x, __hip_bfloat16* __restrict__ A1,
    const float* __restrict__ W1l, const float* __restrict__ W1r,
    const float* __restrict__ W2l, const float* __restrict__ W2r,
    __hip_bfloat16* __restrict__ W1t, __hip_bfloat16* __restrict__ W2t,
    int* __restrict__ cnt, int* __restrict__ total) {
    int b = blockIdx.x;
    if (b < PB_ZERO) {
        int i = b * 256 + threadIdx.x;
        if (i < N_NODES) cnt[i] = 0;
        if (b == 0 && threadIdx.x == 0) *total = 0;
    } else if (b < PB_W1) {
        // W1: [128,256] src; dst W1t[n*256 + half*128 + k]
        int reg = b - PB_ZERO;                 // 0..255
        int half = reg >> 7;                   // 0: W1l, 1: W1r
        int t = (reg & 127) * 256 + threadIdx.x;   // 0..32767
        int k = t >> 8, n = t & 255;
        const float* src = half ? W1r : W1l;
        W1t[n * 256 + half * 128 + k] = __float2bfloat16(src[t]);
    } else if (b < PB_W2) {
        // W2: [256,128] src; dst W2t[(half*128+n)*256 + k]
        int reg = b - PB_W1;
        int half = reg >> 7;                   // 0: W2l, 1: W2r
        int t = (reg & 127) * 256 + threadIdx.x;
        int k = t >> 7, n = t & 127;
        const float* src = half ? W2r : W2l;
        W2t[(size_t)(half * 128 + n) * 256 + k] = __float2bfloat16(src[t]);
    } else {
        int t = (b - PB_W2) * 256 + threadIdx.x;
        if (t >= N_NODES * 32) return;
        int row = t >> 5, c = (t & 31) * 4;
        float4 v = *(const float4*)(x + (size_t)row * 128 + c);
        __hip_bfloat16* d = A1 + (size_t)row * 256 + 128 + c;
        __hip_bfloat162 p0, p1;
        p0.x = __float2bfloat16(v.x); p0.y = __float2bfloat16(v.y);
        p1.x = __float2bfloat16(v.z); p1.y = __float2bfloat16(v.w);
        *(__hip_bfloat162*)d = p0;
        *(__hip_bfloat162*)(d + 2) = p1;
    }
}

// ---------------- CSR build ----------------

__global__ void count_deg(const int* __restrict__ dst, int* __restrict__ cnt, int E) {
    int e = blockIdx.x * blockDim.x + threadIdx.x;
    if (e < E) atomicAdd(&cnt[dst[e]], 1);
}

// per-block exclusive scan + atomic global base; CSR segment ORDER is
// irrelevant for gather-mean, so nondeterministic bases are fine.
__global__ __launch_bounds__(256) void assign_offsets(
    const int* __restrict__ cnt, int* __restrict__ row_ptr,
    int* __restrict__ cursor, int* __restrict__ total, int n) {
    __shared__ int tmp[256];
    __shared__ int sbase;
    int t = threadIdx.x, g = blockIdx.x * 256 + t;
    int v = (g < n) ? cnt[g] : 0;
    tmp[t] = v; __syncthreads();
    for (int off = 1; off < 256; off <<= 1) {
        int u = (t >= off) ? tmp[t - off] : 0;
        __syncthreads();
        tmp[t] += u;
        __syncthreads();
    }
    if (t == 255) sbase = atomicAdd(total, tmp[255]);
    __syncthreads();
    if (g < n) {
        int e = sbase + tmp[t] - v;
        row_ptr[g] = e;
        cursor[g] = e;
    }
}

// cursor holds absolute write position (pre-initialized to row_ptr)
__global__ void fill_csr(const int* __restrict__ srcI, const int* __restrict__ dstI,
                         int* __restrict__ cursor, int* __restrict__ col, int E) {
    int e = blockIdx.x * blockDim.x + threadIdx.x;
    if (e < E) {
        int pos = atomicAdd(&cursor[dstI[e]], 1);
        col[pos] = srcI[e];
    }
}

// ---------------- mean aggregation ----------------
// 16 lanes/node (8 ch each, one 16B bf16x8 load), 4 nodes/wave, 16 nodes/block,
// 4-edge unroll -> 16 outstanding 16B gathers per wave.
// FINAL=0: write 8 bf16 (16B). FINAL=1: out = pre + mean, fp32 (2x16B).
template <int FINAL>
__global__ __launch_bounds__(256) void aggregate_mean(
    const __hip_bfloat16* __restrict__ feat, int featStride,
    const int* __restrict__ row_ptr, const int* __restrict__ deg,
    const int* __restrict__ col,
    void* __restrict__ outp, int outStride,
    const float* __restrict__ pre, int nNodes) {
    int node = blockIdx.x * 16 + (threadIdx.x >> 4);
    int sl   = threadIdx.x & 15;
    if (node >= nNodes) return;
    int beg = row_ptr[node];
    int d   = deg[node];
    const __hip_bfloat16* base = feat + sl * 8;
    float a[8];
    #pragma unroll
    for (int c = 0; c < 8; ++c) a[c] = 0.f;
    int j = 0;
    for (; j + 4 <= d; j += 4) {
        int s0 = col[beg + j];
        int s1 = col[beg + j + 1];
        int s2 = col[beg + j + 2];
        int s3 = col[beg + j + 3];
        short8 v0 = *(const short8*)(base + (size_t)s0 * featStride);
        short8 v1 = *(const short8*)(base + (size_t)s1 * featStride);
        short8 v2 = *(const short8*)(base + (size_t)s2 * featStride);
        short8 v3 = *(const short8*)(base + (size_t)s3 * featStride);
        #pragma unroll
        for (int c = 0; c < 8; ++c)
            a[c] += (bf2f(v0[c]) + bf2f(v1[c])) + (bf2f(v2[c]) + bf2f(v3[c]));
    }
    for (; j < d; ++j) {
        short8 v = *(const short8*)(base + (size_t)col[beg + j] * featStride);
        #pragma unroll
        for (int c = 0; c < 8; ++c) a[c] += bf2f(v[c]);
    }
    float inv = 1.f / (float)max(d, 1);
    #pragma unroll
    for (int c = 0; c < 8; ++c) a[c] *= inv;
    if (FINAL) {
        const float* pp = pre + (size_t)node * 128 + sl * 8;
        float* op = (float*)outp + (size_t)node * 128 + sl * 8;
        float4 p0 = *(const float4*)pp;
        float4 p1 = *(const float4*)(pp + 4);
        *(float4*)op       = make_float4(a[0] + p0.x, a[1] + p0.y, a[2] + p0.z, a[3] + p0.w);
        *(float4*)(op + 4) = make_float4(a[4] + p1.x, a[5] + p1.y, a[6] + p1.z, a[7] + p1.w);
    } else {
        __hip_bfloat16* o = (__hip_bfloat16*)outp + (size_t)node * outStride + sl * 8;
        short8 q;
        #pragma unroll
        for (int c = 0; c < 8; ++c) {
            union { __hip_bfloat16 b; short s; } cv;
            cv.b = __float2bfloat16(a[c]);
            q[c] = cv.s;
        }
        *(short8*)o = q;
    }
}

// ---------------- bf16 MFMA GEMM ----------------
// 128x128 tile, BK=64, global_load_lds width=16, XOR chunk swizzle.
// mode 0 (layer1): outBf = relu(A@Bt^T + bias)
// mode 1 (layer2 fused, grid.y=2):
//   y==0: outBf = bf16(A@W2l^T); y==1: outF = A@W2r^T + bias

#define GBM 128
#define GBN 128
#define GBK 64

__device__ __forceinline__ void gload16(const void* g, void* l) {
    typedef const __attribute__((address_space(1))) unsigned int* gp_t;
    typedef __attribute__((address_space(3))) unsigned int* lp_t;
    __builtin_amdgcn_global_load_lds((gp_t)g, (lp_t)l, 16, 0, 0);
}

__global__ __launch_bounds__(256) void gemm_mfma(
    const __hip_bfloat16* __restrict__ A, int lda,
    const __hip_bfloat16* __restrict__ Bt,    // [Ntot][K] row-major, ld=K
    const float* __restrict__ bias,
    __hip_bfloat16* __restrict__ outBf, int outBfStride,
    float* __restrict__ outF,
    int M, int K, int mode) {
    __shared__ __hip_bfloat16 Als[GBM * GBK];
    __shared__ __hip_bfloat16 Bls[GBN * GBK];

    int tid  = threadIdx.x;
    int wave = tid >> 6, lane = tid & 63;
    int wm = wave >> 1, wn = wave & 1;
    int mb = blockIdx.x * GBM, nb = blockIdx.y * GBN;

    int srow_base = wave * 32;
    int lrow = lane >> 3;
    int pch  = lane & 7;

    f32x4 acc[4][4];
    #pragma unroll
    for (int i = 0; i < 4; ++i)
        #pragma unroll
        for (int j = 0; j < 4; ++j)
            acc[i][j] = (f32x4){0.f, 0.f, 0.f, 0.f};

    for (int kt = 0; kt < K; kt += GBK) {
        #pragma unroll
        for (int t = 0; t < 4; ++t) {
            int rloc = srow_base + t * 8 + lrow;
            int lch  = pch ^ (rloc & 7);
            int ga_row = mb + rloc; if (ga_row >= M) ga_row = M - 1;
            const __hip_bfloat16* ga = A + (size_t)ga_row * lda + kt + lch * 8;
            gload16(ga, &Als[(srow_base + t * 8) * GBK]);
            const __hip_bfloat16* gb = Bt + (size_t)(nb + rloc) * K + kt + lch * 8;
            gload16(gb, &Bls[(srow_base + t * 8) * GBK]);
        }
        __syncthreads();

        #pragma unroll
        for (int ks = 0; ks < GBK; ks += 32) {
            int chunkL = (ks >> 3) + (lane >> 4);
            short8 af[4], bf[4];
            #pragma unroll
            for (int i = 0; i < 4; ++i) {
                int row = wm * 64 + i * 16 + (lane & 15);
                int pc  = chunkL ^ (row & 7);
                af[i] = *(const short8*)&Als[row * GBK + pc * 8];
            }
            #pragma unroll
            for (int j = 0; j < 4; ++j) {
                int row = wn * 64 + j * 16 + (lane & 15);
                int pc  = chunkL ^ (row & 7);
                bf[j] = *(const short8*)&Bls[row * GBK + pc * 8];
            }
            #pragma unroll
            for (int i = 0; i < 4; ++i)
                #pragma unroll
                for (int j = 0; j < 4; ++j)
                    acc[i][j] = __builtin_amdgcn_mfma_f32_16x16x32_bf16(
                        af[i], bf[j], acc[i][j], 0, 0, 0);
        }
        __syncthreads();
    }

    // epilogue: C/D layout col=lane&15, row=(lane>>4)*4+reg
    int cn[4];
    float bc[4];
    #pragma unroll
    for (int j = 0; j < 4; ++j) {
        cn[j] = wn * 64 + j * 16 + (lane & 15);
        bc[j] = 0.f;
    }
    if (mode == 0) {
        #pragma unroll
        for (int j = 0; j < 4; ++j) bc[j] = bias[nb + cn[j]];
        #pragma unroll
        for (int i = 0; i < 4; ++i)
            #pragma unroll
            for (int r = 0; r < 4; ++r) {
                int row = mb + wm * 64 + i * 16 + (lane >> 4) * 4 + r;
                if (row >= M) continue;
                #pragma unroll
                for (int j = 0; j < 4; ++j) {
                    float v = fmaxf(acc[i][j][r] + bc[j], 0.f);
                    outBf[(size_t)row * outBfStride + nb + cn[j]] = __float2bfloat16(v);
                }
            }
    } else if (blockIdx.y == 0) {
        #pragma unroll
        for (int i = 0; i < 4; ++i)
            #pragma unroll
            for (int r = 0; r < 4; ++r) {
                int row = mb + wm * 64 + i * 16 + (lane >> 4) * 4 + r;
                if (row >= M) continue;
                #pragma unroll
                for (int j = 0; j < 4; ++j)
                    outBf[(size_t)row * 128 + cn[j]] = __float2bfloat16(acc[i][j][r]);
            }
    } else {
        #pragma unroll
        for (int j = 0; j < 4; ++j) bc[j] = bias[cn[j]];
        #pragma unroll
        for (int i = 0; i < 4; ++i)
            #pragma unroll
            for (int r = 0; r < 4; ++r) {
                int row = mb + wm * 64 + i * 16 + (lane >> 4) * 4 + r;
                if (row >= M) continue;
                #pragma unroll
                for (int j = 0; j < 4; ++j)
                    outF[(size_t)row * 128 + cn[j]] = acc[i][j][r] + bc[j];
            }
    }
}

extern "C" void kernel_launch(void* const* d_in, const int* in_sizes, int n_in,
                              void* d_out, int out_size, void* d_ws, size_t ws_size,
                              hipStream_t stream) {
    const float* x    = (const float*)d_in[0];
    const int*   ei   = (const int*)d_in[1];
    const float* W1l  = (const float*)d_in[2];
    const float* b1   = (const float*)d_in[3];
    const float* W1r  = (const float*)d_in[4];
    const float* W2l  = (const float*)d_in[5];
    const float* b2   = (const float*)d_in[6];
    const float* W2r  = (const float*)d_in[7];
    float* out = (float*)d_out;

    const int E = N_EDGES;
    const int N = N_NODES;
    const int* srcI = ei;
    const int* dstI = ei + E;

    // workspace layout (bytes)
    char* w = (char*)d_ws;
    int*            cnt     = (int*)(w + 0);                   // 200000
    int*            row_ptr = (int*)(w + 204800);              // 200000
    int*            col     = (int*)(w + 409600);              // 2400000
    int*            total   = (int*)(w + 2809856);             // 4
    __hip_bfloat16* W1t     = (__hip_bfloat16*)(w + 2818048);  // [256][256]
    __hip_bfloat16* W2t     = (__hip_bfloat16*)(w + 2949120);  // [256][256]
    int*            cursor  = (int*)(w + 3080192);             // 200000
    __hip_bfloat16* A1      = (__hip_bfloat16*)(w + 3280896);  // [50000][256]
    __hip_bfloat16* h_bf    = (__hip_bfloat16*)(w + 28880896); // [50000][256]
    __hip_bfloat16* hp_bf   = (__hip_bfloat16*)(w + 54480896); // [50000][128]
    float*          pre     = (float*)(w + 67280896);          // [50000][128] fp32

    // ---- prep: zero cnt/total + weight transposes + x->bf16 (1 launch) ----
    prep<<<PB_X, 256, 0, stream>>>(x, A1, W1l, W1r, W2l, W2r, W1t, W2t, cnt, total);

    // ---- CSR build (3 launches) ----
    count_deg<<<(E + 255) / 256, 256, 0, stream>>>(dstI, cnt, E);
    assign_offsets<<<(N + 255) / 256, 256, 0, stream>>>(cnt, row_ptr, cursor, total, N);
    fill_csr<<<(E + 255) / 256, 256, 0, stream>>>(srcI, dstI, cursor, col, E);

    // ---- layer 1 ----
    aggregate_mean<0><<<(N + 15) / 16, 256, 0, stream>>>(
        A1 + 128, 256, row_ptr, cnt, col, (void*)A1, 256, nullptr, N);
    {
        dim3 grid((N + GBM - 1) / GBM, HID_C / GBN);
        gemm_mfma<<<grid, 256, 0, stream>>>(A1, 256, W1t, b1,
                                            h_bf, 256, nullptr, N, 256, 0);
    }

    // ---- layer 2 fused projection ----
    {
        dim3 grid((N + GBM - 1) / GBM, 2);
        gemm_mfma<<<grid, 256, 0, stream>>>(h_bf, 256, W2t, b2,
                                            hp_bf, 128, pre, N, 256, 1);
    }
    // ---- final: out = pre + mean(hp) ----
    aggregate_mean<1><<<(N + 15) / 16, 256, 0, stream>>>(
        hp_bf, 128, row_ptr, cnt, col, (void*)out, 128, pre, N);
}

// Round 7
// 243.285 us; speedup vs baseline: 9.7335x; 1.0079x over previous
//
#include <hip/hip_runtime.h>
#include <hip/hip_bf16.h>

// GraphSAGE 2-layer forward, MI355X. R7:
//  - count_deg merged into prep (cnt zeroed via hipMemsetAsync before launch;
//    count blocks first so atomics overlap streaming transposes/cvt).
//  - aggregate: software-pipelined 4-edge groups (next group's col+feature
//    loads issued while accumulating current) -> index latency hidden,
//    8 gathers in flight; parallel-load tail.
//  7 kernels + 1 memset: memset, prep(+count), assign_offsets, fill_csr,
//  agg1, gemm1, gemm2(fused y), agg2(final).

#define N_NODES 50000
#define IN_C    128
#define HID_C   256
#define OUT_C   128
#define N_EDGES 600000

// prep block partition: count first (latency-bound), then streaming
#define PB_CNT  2344                 // ceil(600000/256)
#define PB_W1   (PB_CNT + 256)       // 2600
#define PB_W2   (PB_W1 + 256)        // 2856
#define PB_X    (PB_W2 + 6250)       // 9106 total

typedef __attribute__((ext_vector_type(8))) short short8;   // 8 bf16 (16B)
typedef __attribute__((ext_vector_type(4))) float f32x4;

__device__ __forceinline__ float bf2f(short s) {
    union { unsigned u; float f; } c;
    c.u = ((unsigned)(unsigned short)s) << 16;
    return c.f;
}

// ---------------- fused prep (+ degree count) ----------------
__global__ __launch_bounds__(256) void prep(
    const float* __restrict__ x, __hip_bfloat16* __restrict__ A1,
    const float* __restrict__ W1l, const float* __restrict__ W1r,
    const float* __restrict__ W2l, const float* __restrict__ W2r,
    __hip_bfloat16* __restrict__ W1t, __hip_bfloat16* __restrict__ W2t,
    const int* __restrict__ dstI, int* __restrict__ cnt) {
    int b = blockIdx.x;
    if (b < PB_CNT) {
        int e = b * 256 + threadIdx.x;
        if (e < N_EDGES) atomicAdd(&cnt[dstI[e]], 1);
    } else if (b < PB_W1) {
        // W1: [128,256] src; dst W1t[n*256 + half*128 + k]
        int reg = b - PB_CNT;                  // 0..255
        int half = reg >> 7;                   // 0: W1l, 1: W1r
        int t = (reg & 127) * 256 + threadIdx.x;   // 0..32767
        int k = t >> 8, n = t & 255;
        const float* src = half ? W1r : W1l;
        W1t[n * 256 + half * 128 + k] = __float2bfloat16(src[t]);
    } else if (b < PB_W2) {
        // W2: [256,128] src; dst W2t[(half*128+n)*256 + k]
        int reg = b - PB_W1;
        int half = reg >> 7;                   // 0: W2l, 1: W2r
        int t = (reg & 127) * 256 + threadIdx.x;
        int k = t >> 7, n = t & 127;
        const float* src = half ? W2r : W2l;
        W2t[(size_t)(half * 128 + n) * 256 + k] = __float2bfloat16(src[t]);
    } else {
        int t = (b - PB_W2) * 256 + threadIdx.x;
        if (t >= N_NODES * 32) return;
        int row = t >> 5, c = (t & 31) * 4;
        float4 v = *(const float4*)(x + (size_t)row * 128 + c);
        __hip_bfloat16* d = A1 + (size_t)row * 256 + 128 + c;
        __hip_bfloat162 p0, p1;
        p0.x = __float2bfloat16(v.x); p0.y = __float2bfloat16(v.y);
        p1.x = __float2bfloat16(v.z); p1.y = __float2bfloat16(v.w);
        *(__hip_bfloat162*)d = p0;
        *(__hip_bfloat162*)(d + 2) = p1;
    }
}

// ---------------- CSR build ----------------
// per-block exclusive scan + atomic global base; CSR segment ORDER is
// irrelevant for gather-mean, so nondeterministic bases are fine.
__global__ __launch_bounds__(256) void assign_offsets(
    const int* __restrict__ cnt, int* __restrict__ row_ptr,
    int* __restrict__ cursor, int* __restrict__ total, int n) {
    __shared__ int tmp[256];
    __shared__ int sbase;
    int t = threadIdx.x, g = blockIdx.x * 256 + t;
    int v = (g < n) ? cnt[g] : 0;
    tmp[t] = v; __syncthreads();
    for (int off = 1; off < 256; off <<= 1) {
        int u = (t >= off) ? tmp[t - off] : 0;
        __syncthreads();
        tmp[t] += u;
        __syncthreads();
    }
    if (t == 255) sbase = atomicAdd(total, tmp[255]);
    __syncthreads();
    if (g < n) {
        int e = sbase + tmp[t] - v;
        row_ptr[g] = e;
        cursor[g] = e;
    }
}

// cursor holds absolute write position (pre-initialized to row_ptr)
__global__ void fill_csr(const int* __restrict__ srcI, const int* __restrict__ dstI,
                         int* __restrict__ cursor, int* __restrict__ col, int E) {
    int e = blockIdx.x * blockDim.x + threadIdx.x;
    if (e < E) {
        int pos = atomicAdd(&cursor[dstI[e]], 1);
        col[pos] = srcI[e];
    }
}

// ---------------- mean aggregation (software-pipelined) ----------------
// 16 lanes/node (8 ch each, 16B bf16x8 loads), 4 nodes/wave, 16 nodes/block.
// Pipeline: group j+4's col+feature loads issued while accumulating group j.
// FINAL=0: write 8 bf16 (16B). FINAL=1: out = pre + mean, fp32 (2x16B).
template <int FINAL>
__global__ __launch_bounds__(256) void aggregate_mean(
    const __hip_bfloat16* __restrict__ feat, int featStride,
    const int* __restrict__ row_ptr, const int* __restrict__ deg,
    const int* __restrict__ col,
    void* __restrict__ outp, int outStride,
    const float* __restrict__ pre, int nNodes) {
    int node = blockIdx.x * 16 + (threadIdx.x >> 4);
    int sl   = threadIdx.x & 15;
    if (node >= nNodes) return;
    int beg = row_ptr[node];
    int d   = deg[node];
    const __hip_bfloat16* base = feat + sl * 8;
    float a[8];
    #pragma unroll
    for (int c = 0; c < 8; ++c) a[c] = 0.f;

    short8 v0, v1, v2, v3;
    int j = 0;
    if (d >= 4) {                       // prologue: load group 0
        int s0 = col[beg + 0], s1 = col[beg + 1];
        int s2 = col[beg + 2], s3 = col[beg + 3];
        v0 = *(const short8*)(base + (size_t)s0 * featStride);
        v1 = *(const short8*)(base + (size_t)s1 * featStride);
        v2 = *(const short8*)(base + (size_t)s2 * featStride);
        v3 = *(const short8*)(base + (size_t)s3 * featStride);
        for (; j + 8 <= d; j += 4) {    // steady state: load j+4, acc j
            int t0 = col[beg + j + 4], t1 = col[beg + j + 5];
            int t2 = col[beg + j + 6], t3 = col[beg + j + 7];
            short8 w0 = *(const short8*)(base + (size_t)t0 * featStride);
            short8 w1 = *(const short8*)(base + (size_t)t1 * featStride);
            short8 w2 = *(const short8*)(base + (size_t)t2 * featStride);
            short8 w3 = *(const short8*)(base + (size_t)t3 * featStride);
            #pragma unroll
            for (int c = 0; c < 8; ++c)
                a[c] += (bf2f(v0[c]) + bf2f(v1[c])) + (bf2f(v2[c]) + bf2f(v3[c]));
            v0 = w0; v1 = w1; v2 = w2; v3 = w3;
        }
        #pragma unroll
        for (int c = 0; c < 8; ++c)     // epilogue: acc last loaded group
            a[c] += (bf2f(v0[c]) + bf2f(v1[c])) + (bf2f(v2[c]) + bf2f(v3[c]));
        j += 4;
    }
    int rem = d - j;                    // 0..3 tail, indices loaded in parallel
    if (rem > 0) {
        int s0 = col[beg + j];
        int s1 = (rem > 1) ? col[beg + j + 1] : s0;
        int s2 = (rem > 2) ? col[beg + j + 2] : s0;
        short8 t0 = *(const short8*)(base + (size_t)s0 * featStride);
        short8 t1 = *(const short8*)(base + (size_t)s1 * featStride);
        short8 t2 = *(const short8*)(base + (size_t)s2 * featStride);
        #pragma unroll
        for (int c = 0; c < 8; ++c) a[c] += bf2f(t0[c]);
        if (rem > 1) {
            #pragma unroll
            for (int c = 0; c < 8; ++c) a[c] += bf2f(t1[c]);
        }
        if (rem > 2) {
            #pragma unroll
            for (int c = 0; c < 8; ++c) a[c] += bf2f(t2[c]);
        }
    }

    float inv = 1.f / (float)max(d, 1);
    #pragma unroll
    for (int c = 0; c < 8; ++c) a[c] *= inv;
    if (FINAL) {
        const float* pp = pre + (size_t)node * 128 + sl * 8;
        float* op = (float*)outp + (size_t)node * 128 + sl * 8;
        float4 p0 = *(const float4*)pp;
        float4 p1 = *(const float4*)(pp + 4);
        *(float4*)op       = make_float4(a[0] + p0.x, a[1] + p0.y, a[2] + p0.z, a[3] + p0.w);
        *(float4*)(op + 4) = make_float4(a[4] + p1.x, a[5] + p1.y, a[6] + p1.z, a[7] + p1.w);
    } else {
        __hip_bfloat16* o = (__hip_bfloat16*)outp + (size_t)node * outStride + sl * 8;
        short8 q;
        #pragma unroll
        for (int c = 0; c < 8; ++c) {
            union { __hip_bfloat16 b; short s; } cv;
            cv.b = __float2bfloat16(a[c]);
            q[c] = cv.s;
        }
        *(short8*)o = q;
    }
}

// ---------------- bf16 MFMA GEMM ----------------
// 128x128 tile, BK=64, global_load_lds width=16, XOR chunk swizzle.
// mode 0 (layer1): outBf = relu(A@Bt^T + bias)
// mode 1 (layer2 fused, grid.y=2):
//   y==0: outBf = bf16(A@W2l^T); y==1: outF = A@W2r^T + bias

#define GBM 128
#define GBN 128
#define GBK 64

__device__ __forceinline__ void gload16(const void* g, void* l) {
    typedef const __attribute__((address_space(1))) unsigned int* gp_t;
    typedef __attribute__((address_space(3))) unsigned int* lp_t;
    __builtin_amdgcn_global_load_lds((gp_t)g, (lp_t)l, 16, 0, 0);
}

__global__ __launch_bounds__(256) void gemm_mfma(
    const __hip_bfloat16* __restrict__ A, int lda,
    const __hip_bfloat16* __restrict__ Bt,    // [Ntot][K] row-major, ld=K
    const float* __restrict__ bias,
    __hip_bfloat16* __restrict__ outBf, int outBfStride,
    float* __restrict__ outF,
    int M, int K, int mode) {
    __shared__ __hip_bfloat16 Als[GBM * GBK];
    __shared__ __hip_bfloat16 Bls[GBN * GBK];

    int tid  = threadIdx.x;
    int wave = tid >> 6, lane = tid & 63;
    int wm = wave >> 1, wn = wave & 1;
    int mb = blockIdx.x * GBM, nb = blockIdx.y * GBN;

    int srow_base = wave * 32;
    int lrow = lane >> 3;
    int pch  = lane & 7;

    f32x4 acc[4][4];
    #pragma unroll
    for (int i = 0; i < 4; ++i)
        #pragma unroll
        for (int j = 0; j < 4; ++j)
            acc[i][j] = (f32x4){0.f, 0.f, 0.f, 0.f};

    for (int kt = 0; kt < K; kt += GBK) {
        #pragma unroll
        for (int t = 0; t < 4; ++t) {
            int rloc = srow_base + t * 8 + lrow;
            int lch  = pch ^ (rloc & 7);
            int ga_row = mb + rloc; if (ga_row >= M) ga_row = M - 1;
            const __hip_bfloat16* ga = A + (size_t)ga_row * lda + kt + lch * 8;
            gload16(ga, &Als[(srow_base + t * 8) * GBK]);
            const __hip_bfloat16* gb = Bt + (size_t)(nb + rloc) * K + kt + lch * 8;
            gload16(gb, &Bls[(srow_base + t * 8) * GBK]);
        }
        __syncthreads();

        #pragma unroll
        for (int ks = 0; ks < GBK; ks += 32) {
            int chunkL = (ks >> 3) + (lane >> 4);
            short8 af[4], bf[4];
            #pragma unroll
            for (int i = 0; i < 4; ++i) {
                int row = wm * 64 + i * 16 + (lane & 15);
                int pc  = chunkL ^ (row & 7);
                af[i] = *(const short8*)&Als[row * GBK + pc * 8];
            }
            #pragma unroll
            for (int j = 0; j < 4; ++j) {
                int row = wn * 64 + j * 16 + (lane & 15);
                int pc  = chunkL ^ (row & 7);
                bf[j] = *(const short8*)&Bls[row * GBK + pc * 8];
            }
            #pragma unroll
            for (int i = 0; i < 4; ++i)
                #pragma unroll
                for (int j = 0; j < 4; ++j)
                    acc[i][j] = __builtin_amdgcn_mfma_f32_16x16x32_bf16(
                        af[i], bf[j], acc[i][j], 0, 0, 0);
        }
        __syncthreads();
    }

    // epilogue: C/D layout col=lane&15, row=(lane>>4)*4+reg
    int cn[4];
    float bc[4];
    #pragma unroll
    for (int j = 0; j < 4; ++j) {
        cn[j] = wn * 64 + j * 16 + (lane & 15);
        bc[j] = 0.f;
    }
    if (mode == 0) {
        #pragma unroll
        for (int j = 0; j < 4; ++j) bc[j] = bias[nb + cn[j]];
        #pragma unroll
        for (int i = 0; i < 4; ++i)
            #pragma unroll
            for (int r = 0; r < 4; ++r) {
                int row = mb + wm * 64 + i * 16 + (lane >> 4) * 4 + r;
                if (row >= M) continue;
                #pragma unroll
                for (int j = 0; j < 4; ++j) {
                    float v = fmaxf(acc[i][j][r] + bc[j], 0.f);
                    outBf[(size_t)row * outBfStride + nb + cn[j]] = __float2bfloat16(v);
                }
            }
    } else if (blockIdx.y == 0) {
        #pragma unroll
        for (int i = 0; i < 4; ++i)
            #pragma unroll
            for (int r = 0; r < 4; ++r) {
                int row = mb + wm * 64 + i * 16 + (lane >> 4) * 4 + r;
                if (row >= M) continue;
                #pragma unroll
                for (int j = 0; j < 4; ++j)
                    outBf[(size_t)row * 128 + cn[j]] = __float2bfloat16(acc[i][j][r]);
            }
    } else {
        #pragma unroll
        for (int j = 0; j < 4; ++j) bc[j] = bias[cn[j]];
        #pragma unroll
        for (int i = 0; i < 4; ++i)
            #pragma unroll
            for (int r = 0; r < 4; ++r) {
                int row = mb + wm * 64 + i * 16 + (lane >> 4) * 4 + r;
                if (row >= M) continue;
                #pragma unroll
                for (int j = 0; j < 4; ++j)
                    outF[(size_t)row * 128 + cn[j]] = acc[i][j][r] + bc[j];
            }
    }
}

extern "C" void kernel_launch(void* const* d_in, const int* in_sizes, int n_in,
                              void* d_out, int out_size, void* d_ws, size_t ws_size,
                              hipStream_t stream) {
    const float* x    = (const float*)d_in[0];
    const int*   ei   = (const int*)d_in[1];
    const float* W1l  = (const float*)d_in[2];
    const float* b1   = (const float*)d_in[3];
    const float* W1r  = (const float*)d_in[4];
    const float* W2l  = (const float*)d_in[5];
    const float* b2   = (const float*)d_in[6];
    const float* W2r  = (const float*)d_in[7];
    float* out = (float*)d_out;

    const int E = N_EDGES;
    const int N = N_NODES;
    const int* srcI = ei;
    const int* dstI = ei + E;

    // workspace layout (bytes)
    char* w = (char*)d_ws;
    int*            cnt     = (int*)(w + 0);                   // 200000
    int*            total   = (int*)(w + 200000);              // 4 (memset with cnt)
    int*            row_ptr = (int*)(w + 204800);              // 200000
    int*            col     = (int*)(w + 409600);              // 2400000
    __hip_bfloat16* W1t     = (__hip_bfloat16*)(w + 2818048);  // [256][256]
    __hip_bfloat16* W2t     = (__hip_bfloat16*)(w + 2949120);  // [256][256]
    int*            cursor  = (int*)(w + 3080192);             // 200000
    __hip_bfloat16* A1      = (__hip_bfloat16*)(w + 3280896);  // [50000][256]
    __hip_bfloat16* h_bf    = (__hip_bfloat16*)(w + 28880896); // [50000][256]
    __hip_bfloat16* hp_bf   = (__hip_bfloat16*)(w + 54480896); // [50000][128]
    float*          pre     = (float*)(w + 67280896);          // [50000][128] fp32

    // ---- zero cnt+total, then fused prep (+degree count) ----
    hipMemsetAsync(cnt, 0, 200004, stream);
    prep<<<PB_X, 256, 0, stream>>>(x, A1, W1l, W1r, W2l, W2r, W1t, W2t, dstI, cnt);

    // ---- CSR build ----
    assign_offsets<<<(N + 255) / 256, 256, 0, stream>>>(cnt, row_ptr, cursor, total, N);
    fill_csr<<<(E + 255) / 256, 256, 0, stream>>>(srcI, dstI, cursor, col, E);

    // ---- layer 1 ----
    aggregate_mean<0><<<(N + 15) / 16, 256, 0, stream>>>(
        A1 + 128, 256, row_ptr, cnt, col, (void*)A1, 256, nullptr, N);
    {
        dim3 grid((N + GBM - 1) / GBM, HID_C / GBN);
        gemm_mfma<<<grid, 256, 0, stream>>>(A1, 256, W1t, b1,
                                            h_bf, 256, nullptr, N, 256, 0);
    }

    // ---- layer 2 fused projection ----
    {
        dim3 grid((N + GBM - 1) / GBM, 2);
        gemm_mfma<<<grid, 256, 0, stream>>>(h_bf, 256, W2t, b2,
                                            hp_bf, 128, pre, N, 256, 1);
    }
    // ---- final: out = pre + mean(hp) ----
    aggregate_mean<1><<<(N + 15) / 16, 256, 0, stream>>>(
        hp_bf, 128, row_ptr, cnt, col, (void*)out, 128, pre, N);
}

// Round 9
// 234.584 us; speedup vs baseline: 10.0946x; 1.0371x over previous
//
#include <hip/hip_runtime.h>
#include <hip/hip_bf16.h>

// GraphSAGE 2-layer forward, MI355X. R9 (= R8 with fp8-decode compile fix):
//  - hp stored fp8 e4m3 -> layer-2 gather touches 1 cacheline/edge (128B).
//  - fp8 decode via __builtin_amdgcn_cvt_pk_f32_fp8 (constant word_sel).

#define N_NODES 50000
#define IN_C    128
#define HID_C   256
#define OUT_C   128
#define N_EDGES 600000

// prep block partition: count first (latency-bound), then streaming
#define PB_CNT  2344                 // ceil(600000/256)
#define PB_W1   (PB_CNT + 256)       // 2600
#define PB_W2   (PB_W1 + 256)        // 2856
#define PB_X    (PB_W2 + 6250)       // 9106 total

typedef __attribute__((ext_vector_type(8))) short short8;   // 8 bf16 (16B)
typedef __attribute__((ext_vector_type(4))) float f32x4;
typedef __attribute__((ext_vector_type(2))) float f32x2;

__device__ __forceinline__ float bf2f(short s) {
    union { unsigned u; float f; } c;
    c.u = ((unsigned)(unsigned short)s) << 16;
    return c.f;
}
__device__ __forceinline__ unsigned f2fp8(float v) {
    return (unsigned)__builtin_amdgcn_cvt_pk_fp8_f32(v, v, 0, false) & 0xffu;
}
// accumulate 4 fp8 bytes (one u32) into a[0..3]
__device__ __forceinline__ void acc_fp8x4(float* a, unsigned u) {
    f32x2 lo = __builtin_amdgcn_cvt_pk_f32_fp8(u, false);
    f32x2 hi = __builtin_amdgcn_cvt_pk_f32_fp8(u, true);
    a[0] += lo[0]; a[1] += lo[1]; a[2] += hi[0]; a[3] += hi[1];
}

// ---------------- fused prep (+ degree count) ----------------
__global__ __launch_bounds__(256) void prep(
    const float* __restrict__ x, __hip_bfloat16* __restrict__ A1,
    const float* __restrict__ W1l, const float* __restrict__ W1r,
    const float* __restrict__ W2l, const float* __restrict__ W2r,
    __hip_bfloat16* __restrict__ W1t, __hip_bfloat16* __restrict__ W2t,
    const int* __restrict__ dstI, int* __restrict__ cnt) {
    int b = blockIdx.x;
    if (b < PB_CNT) {
        int e = b * 256 + threadIdx.x;
        if (e < N_EDGES) atomicAdd(&cnt[dstI[e]], 1);
    } else if (b < PB_W1) {
        int reg = b - PB_CNT;
        int half = reg >> 7;
        int t = (reg & 127) * 256 + threadIdx.x;
        int k = t >> 8, n = t & 255;
        const float* src = half ? W1r : W1l;
        W1t[n * 256 + half * 128 + k] = __float2bfloat16(src[t]);
    } else if (b < PB_W2) {
        int reg = b - PB_W1;
        int half = reg >> 7;
        int t = (reg & 127) * 256 + threadIdx.x;
        int k = t >> 7, n = t & 127;
        const float* src = half ? W2r : W2l;
        W2t[(size_t)(half * 128 + n) * 256 + k] = __float2bfloat16(src[t]);
    } else {
        int t = (b - PB_W2) * 256 + threadIdx.x;
        if (t >= N_NODES * 32) return;
        int row = t >> 5, c = (t & 31) * 4;
        float4 v = *(const float4*)(x + (size_t)row * 128 + c);
        __hip_bfloat16* d = A1 + (size_t)row * 256 + 128 + c;
        __hip_bfloat162 p0, p1;
        p0.x = __float2bfloat16(v.x); p0.y = __float2bfloat16(v.y);
        p1.x = __float2bfloat16(v.z); p1.y = __float2bfloat16(v.w);
        *(__hip_bfloat162*)d = p0;
        *(__hip_bfloat162*)(d + 2) = p1;
    }
}

// ---------------- CSR build ----------------
__global__ __launch_bounds__(256) void assign_offsets(
    const int* __restrict__ cnt, int* __restrict__ row_ptr,
    int* __restrict__ cursor, int* __restrict__ total, int n) {
    __shared__ int tmp[256];
    __shared__ int sbase;
    int t = threadIdx.x, g = blockIdx.x * 256 + t;
    int v = (g < n) ? cnt[g] : 0;
    tmp[t] = v; __syncthreads();
    for (int off = 1; off < 256; off <<= 1) {
        int u = (t >= off) ? tmp[t - off] : 0;
        __syncthreads();
        tmp[t] += u;
        __syncthreads();
    }
    if (t == 255) sbase = atomicAdd(total, tmp[255]);
    __syncthreads();
    if (g < n) {
        int e = sbase + tmp[t] - v;
        row_ptr[g] = e;
        cursor[g] = e;
    }
}

__global__ void fill_csr(const int* __restrict__ srcI, const int* __restrict__ dstI,
                         int* __restrict__ cursor, int* __restrict__ col, int E) {
    int e = blockIdx.x * blockDim.x + threadIdx.x;
    if (e < E) {
        int pos = atomicAdd(&cursor[dstI[e]], 1);
        col[pos] = srcI[e];
    }
}

// ---------------- layer-1 mean aggregation (bf16 gather) ----------------
// 16 lanes/node (8 ch each, 16B bf16x8 loads), 4 nodes/wave, 16 nodes/block.
__global__ __launch_bounds__(256) void aggregate_bf16(
    const __hip_bfloat16* __restrict__ feat, int featStride,
    const int* __restrict__ row_ptr, const int* __restrict__ deg,
    const int* __restrict__ col,
    __hip_bfloat16* __restrict__ outp, int outStride, int nNodes) {
    int node = blockIdx.x * 16 + (threadIdx.x >> 4);
    int sl   = threadIdx.x & 15;
    if (node >= nNodes) return;
    int beg = row_ptr[node];
    int d   = deg[node];
    const __hip_bfloat16* base = feat + sl * 8;
    float a[8];
    #pragma unroll
    for (int c = 0; c < 8; ++c) a[c] = 0.f;

    short8 v0, v1, v2, v3;
    int j = 0;
    if (d >= 4) {
        int s0 = col[beg + 0], s1 = col[beg + 1];
        int s2 = col[beg + 2], s3 = col[beg + 3];
        v0 = *(const short8*)(base + (size_t)s0 * featStride);
        v1 = *(const short8*)(base + (size_t)s1 * featStride);
        v2 = *(const short8*)(base + (size_t)s2 * featStride);
        v3 = *(const short8*)(base + (size_t)s3 * featStride);
        for (; j + 8 <= d; j += 4) {
            int t0 = col[beg + j + 4], t1 = col[beg + j + 5];
            int t2 = col[beg + j + 6], t3 = col[beg + j + 7];
            short8 w0 = *(const short8*)(base + (size_t)t0 * featStride);
            short8 w1 = *(const short8*)(base + (size_t)t1 * featStride);
            short8 w2 = *(const short8*)(base + (size_t)t2 * featStride);
            short8 w3 = *(const short8*)(base + (size_t)t3 * featStride);
            #pragma unroll
            for (int c = 0; c < 8; ++c)
                a[c] += (bf2f(v0[c]) + bf2f(v1[c])) + (bf2f(v2[c]) + bf2f(v3[c]));
            v0 = w0; v1 = w1; v2 = w2; v3 = w3;
        }
        #pragma unroll
        for (int c = 0; c < 8; ++c)
            a[c] += (bf2f(v0[c]) + bf2f(v1[c])) + (bf2f(v2[c]) + bf2f(v3[c]));
        j += 4;
    }
    int rem = d - j;
    if (rem > 0) {
        int s0 = col[beg + j];
        int s1 = (rem > 1) ? col[beg + j + 1] : s0;
        int s2 = (rem > 2) ? col[beg + j + 2] : s0;
        short8 t0 = *(const short8*)(base + (size_t)s0 * featStride);
        short8 t1 = *(const short8*)(base + (size_t)s1 * featStride);
        short8 t2 = *(const short8*)(base + (size_t)s2 * featStride);
        #pragma unroll
        for (int c = 0; c < 8; ++c) a[c] += bf2f(t0[c]);
        if (rem > 1) {
            #pragma unroll
            for (int c = 0; c < 8; ++c) a[c] += bf2f(t1[c]);
        }
        if (rem > 2) {
            #pragma unroll
            for (int c = 0; c < 8; ++c) a[c] += bf2f(t2[c]);
        }
    }

    float inv = 1.f / (float)max(d, 1);
    __hip_bfloat16* o = outp + (size_t)node * outStride + sl * 8;
    short8 q;
    #pragma unroll
    for (int c = 0; c < 8; ++c) {
        union { __hip_bfloat16 b; short s; } cv;
        cv.b = __float2bfloat16(a[c] * inv);
        q[c] = cv.s;
    }
    *(short8*)o = q;
}

// ---------------- final aggregation (fp8 gather, 1 line/edge) ----------------
// 16 lanes/node, each loads 8 fp8 ch (8B uint2); out = pre + mean (fp32).
__global__ __launch_bounds__(256) void aggregate_fp8_final(
    const unsigned char* __restrict__ feat,   // [n][128] fp8 e4m3
    const int* __restrict__ row_ptr, const int* __restrict__ deg,
    const int* __restrict__ col,
    float* __restrict__ outp, const float* __restrict__ pre, int nNodes) {
    int node = blockIdx.x * 16 + (threadIdx.x >> 4);
    int sl   = threadIdx.x & 15;
    if (node >= nNodes) return;
    int beg = row_ptr[node];
    int d   = deg[node];
    const unsigned char* base = feat + sl * 8;
    float a[8];
    #pragma unroll
    for (int c = 0; c < 8; ++c) a[c] = 0.f;

    uint2 v0, v1, v2, v3;
    int j = 0;
    if (d >= 4) {
        int s0 = col[beg + 0], s1 = col[beg + 1];
        int s2 = col[beg + 2], s3 = col[beg + 3];
        v0 = *(const uint2*)(base + (size_t)s0 * 128);
        v1 = *(const uint2*)(base + (size_t)s1 * 128);
        v2 = *(const uint2*)(base + (size_t)s2 * 128);
        v3 = *(const uint2*)(base + (size_t)s3 * 128);
        for (; j + 8 <= d; j += 4) {
            int t0 = col[beg + j + 4], t1 = col[beg + j + 5];
            int t2 = col[beg + j + 6], t3 = col[beg + j + 7];
            uint2 w0 = *(const uint2*)(base + (size_t)t0 * 128);
            uint2 w1 = *(const uint2*)(base + (size_t)t1 * 128);
            uint2 w2 = *(const uint2*)(base + (size_t)t2 * 128);
            uint2 w3 = *(const uint2*)(base + (size_t)t3 * 128);
            acc_fp8x4(a,     v0.x); acc_fp8x4(a,     v1.x);
            acc_fp8x4(a,     v2.x); acc_fp8x4(a,     v3.x);
            acc_fp8x4(a + 4, v0.y); acc_fp8x4(a + 4, v1.y);
            acc_fp8x4(a + 4, v2.y); acc_fp8x4(a + 4, v3.y);
            v0 = w0; v1 = w1; v2 = w2; v3 = w3;
        }
        acc_fp8x4(a,     v0.x); acc_fp8x4(a,     v1.x);
        acc_fp8x4(a,     v2.x); acc_fp8x4(a,     v3.x);
        acc_fp8x4(a + 4, v0.y); acc_fp8x4(a + 4, v1.y);
        acc_fp8x4(a + 4, v2.y); acc_fp8x4(a + 4, v3.y);
        j += 4;
    }
    for (; j < d; ++j) {
        uint2 v = *(const uint2*)(base + (size_t)col[beg + j] * 128);
        acc_fp8x4(a, v.x);
        acc_fp8x4(a + 4, v.y);
    }

    float inv = 1.f / (float)max(d, 1);
    const float* pp = pre + (size_t)node * 128 + sl * 8;
    float* op = outp + (size_t)node * 128 + sl * 8;
    float4 p0 = *(const float4*)pp;
    float4 p1 = *(const float4*)(pp + 4);
    *(float4*)op       = make_float4(a[0] * inv + p0.x, a[1] * inv + p0.y,
                                     a[2] * inv + p0.z, a[3] * inv + p0.w);
    *(float4*)(op + 4) = make_float4(a[4] * inv + p1.x, a[5] * inv + p1.y,
                                     a[6] * inv + p1.z, a[7] * inv + p1.w);
}

// ---------------- bf16 MFMA GEMM ----------------
// mode 0 (layer1): outBf = relu(A@Bt^T + bias), stride 256
// mode 1 (layer2 fused, grid.y=2):
//   y==0: outF8 = fp8(A@W2l^T)  [50000][128]
//   y==1: outF  = A@W2r^T + bias (fp32)

#define GBM 128
#define GBN 128
#define GBK 64

__device__ __forceinline__ void gload16(const void* g, void* l) {
    typedef const __attribute__((address_space(1))) unsigned int* gp_t;
    typedef __attribute__((address_space(3))) unsigned int* lp_t;
    __builtin_amdgcn_global_load_lds((gp_t)g, (lp_t)l, 16, 0, 0);
}

__global__ __launch_bounds__(256) void gemm_mfma(
    const __hip_bfloat16* __restrict__ A, int lda,
    const __hip_bfloat16* __restrict__ Bt,
    const float* __restrict__ bias,
    __hip_bfloat16* __restrict__ outBf,
    unsigned char* __restrict__ outF8,
    float* __restrict__ outF,
    int M, int K, int mode) {
    __shared__ __hip_bfloat16 Als[GBM * GBK];
    __shared__ __hip_bfloat16 Bls[GBN * GBK];

    int tid  = threadIdx.x;
    int wave = tid >> 6, lane = tid & 63;
    int wm = wave >> 1, wn = wave & 1;
    int mb = blockIdx.x * GBM, nb = blockIdx.y * GBN;

    int srow_base = wave * 32;
    int lrow = lane >> 3;
    int pch  = lane & 7;

    f32x4 acc[4][4];
    #pragma unroll
    for (int i = 0; i < 4; ++i)
        #pragma unroll
        for (int j = 0; j < 4; ++j)
            acc[i][j] = (f32x4){0.f, 0.f, 0.f, 0.f};

    for (int kt = 0; kt < K; kt += GBK) {
        #pragma unroll
        for (int t = 0; t < 4; ++t) {
            int rloc = srow_base + t * 8 + lrow;
            int lch  = pch ^ (rloc & 7);
            int ga_row = mb + rloc; if (ga_row >= M) ga_row = M - 1;
            const __hip_bfloat16* ga = A + (size_t)ga_row * lda + kt + lch * 8;
            gload16(ga, &Als[(srow_base + t * 8) * GBK]);
            const __hip_bfloat16* gb = Bt + (size_t)(nb + rloc) * K + kt + lch * 8;
            gload16(gb, &Bls[(srow_base + t * 8) * GBK]);
        }
        __syncthreads();

        #pragma unroll
        for (int ks = 0; ks < GBK; ks += 32) {
            int chunkL = (ks >> 3) + (lane >> 4);
            short8 af[4], bf[4];
            #pragma unroll
            for (int i = 0; i < 4; ++i) {
                int row = wm * 64 + i * 16 + (lane & 15);
                int pc  = chunkL ^ (row & 7);
                af[i] = *(const short8*)&Als[row * GBK + pc * 8];
            }
            #pragma unroll
            for (int j = 0; j < 4; ++j) {
                int row = wn * 64 + j * 16 + (lane & 15);
                int pc  = chunkL ^ (row & 7);
                bf[j] = *(const short8*)&Bls[row * GBK + pc * 8];
            }
            #pragma unroll
            for (int i = 0; i < 4; ++i)
                #pragma unroll
                for (int j = 0; j < 4; ++j)
                    acc[i][j] = __builtin_amdgcn_mfma_f32_16x16x32_bf16(
                        af[i], bf[j], acc[i][j], 0, 0, 0);
        }
        __syncthreads();
    }

    // epilogue: C/D layout col=lane&15, row=(lane>>4)*4+reg
    int cn[4];
    float bc[4];
    #pragma unroll
    for (int j = 0; j < 4; ++j) {
        cn[j] = wn * 64 + j * 16 + (lane & 15);
        bc[j] = 0.f;
    }
    if (mode == 0) {
        #pragma unroll
        for (int j = 0; j < 4; ++j) bc[j] = bias[nb + cn[j]];
        #pragma unroll
        for (int i = 0; i < 4; ++i)
            #pragma unroll
            for (int r = 0; r < 4; ++r) {
                int row = mb + wm * 64 + i * 16 + (lane >> 4) * 4 + r;
                if (row >= M) continue;
                #pragma unroll
                for (int j = 0; j < 4; ++j) {
                    float v = fmaxf(acc[i][j][r] + bc[j], 0.f);
                    outBf[(size_t)row * 256 + nb + cn[j]] = __float2bfloat16(v);
                }
            }
    } else if (blockIdx.y == 0) {
        #pragma unroll
        for (int i = 0; i < 4; ++i)
            #pragma unroll
            for (int r = 0; r < 4; ++r) {
                int row = mb + wm * 64 + i * 16 + (lane >> 4) * 4 + r;
                if (row >= M) continue;
                #pragma unroll
                for (int j = 0; j < 4; ++j)
                    outF8[(size_t)row * 128 + cn[j]] = (unsigned char)f2fp8(acc[i][j][r]);
            }
    } else {
        #pragma unroll
        for (int j = 0; j < 4; ++j) bc[j] = bias[cn[j]];
        #pragma unroll
        for (int i = 0; i < 4; ++i)
            #pragma unroll
            for (int r = 0; r < 4; ++r) {
                int row = mb + wm * 64 + i * 16 + (lane >> 4) * 4 + r;
                if (row >= M) continue;
                #pragma unroll
                for (int j = 0; j < 4; ++j)
                    outF[(size_t)row * 128 + cn[j]] = acc[i][j][r] + bc[j];
            }
    }
}

extern "C" void kernel_launch(void* const* d_in, const int* in_sizes, int n_in,
                              void* d_out, int out_size, void* d_ws, size_t ws_size,
                              hipStream_t stream) {
    const float* x    = (const float*)d_in[0];
    const int*   ei   = (const int*)d_in[1];
    const float* W1l  = (const float*)d_in[2];
    const float* b1   = (const float*)d_in[3];
    const float* W1r  = (const float*)d_in[4];
    const float* W2l  = (const float*)d_in[5];
    const float* b2   = (const float*)d_in[6];
    const float* W2r  = (const float*)d_in[7];
    float* out = (float*)d_out;

    const int E = N_EDGES;
    const int N = N_NODES;
    const int* srcI = ei;
    const int* dstI = ei + E;

    // workspace layout (bytes)
    char* w = (char*)d_ws;
    int*            cnt     = (int*)(w + 0);                   // 200000
    int*            total   = (int*)(w + 200000);              // 4 (memset with cnt)
    int*            row_ptr = (int*)(w + 204800);              // 200000
    int*            col     = (int*)(w + 409600);              // 2400000
    __hip_bfloat16* W1t     = (__hip_bfloat16*)(w + 2818048);  // [256][256]
    __hip_bfloat16* W2t     = (__hip_bfloat16*)(w + 2949120);  // [256][256]
    int*            cursor  = (int*)(w + 3080192);             // 200000
    __hip_bfloat16* A1      = (__hip_bfloat16*)(w + 3280896);  // [50000][256]
    __hip_bfloat16* h_bf    = (__hip_bfloat16*)(w + 28880896); // [50000][256]
    unsigned char*  hp_f8   = (unsigned char*)(w + 54480896);  // [50000][128] fp8
    float*          pre     = (float*)(w + 67280896);          // [50000][128] fp32

    // ---- zero cnt+total, then fused prep (+degree count) ----
    hipMemsetAsync(cnt, 0, 200004, stream);
    prep<<<PB_X, 256, 0, stream>>>(x, A1, W1l, W1r, W2l, W2r, W1t, W2t, dstI, cnt);

    // ---- CSR build ----
    assign_offsets<<<(N + 255) / 256, 256, 0, stream>>>(cnt, row_ptr, cursor, total, N);
    fill_csr<<<(E + 255) / 256, 256, 0, stream>>>(srcI, dstI, cursor, col, E);

    // ---- layer 1 ----
    aggregate_bf16<<<(N + 15) / 16, 256, 0, stream>>>(
        A1 + 128, 256, row_ptr, cnt, col, A1, 256, N);
    {
        dim3 grid((N + GBM - 1) / GBM, HID_C / GBN);
        gemm_mfma<<<grid, 256, 0, stream>>>(A1, 256, W1t, b1,
                                            h_bf, nullptr, nullptr, N, 256, 0);
    }

    // ---- layer 2 fused projection (y0 -> hp fp8, y1 -> pre fp32) ----
    {
        dim3 grid((N + GBM - 1) / GBM, 2);
        gemm_mfma<<<grid, 256, 0, stream>>>(h_bf, 256, W2t, b2,
                                            nullptr, hp_f8, pre, N, 256, 1);
    }
    // ---- final: out = pre + mean(hp) ----
    aggregate_fp8_final<<<(N + 15) / 16, 256, 0, stream>>>(
        hp_f8, row_ptr, cnt, col, out, pre, N);
}